// Round 8
// baseline (225.227 us; speedup 1.0000x reference)
//
#include <hip/hip_runtime.h>
#include <hip/hip_fp16.h>

// ---------------------------------------------------------------------------
// GCN 2-layer forward: out = A_hat @ relu(A_hat @ (x@W1) + b1) @ W2 + b2
// A_hat = D^-1/2 (A + I) D^-1/2.
// Layer-2 uses the algebra swap out = (A_hat @ relu(agg1)) @ W2 + b2 so BOTH
// gathers run on 64-wide 128B-aligned fp16 rows. Gather = quad-node waves
// (4 independent row loads in flight per lane -> latency-MLP fix).
// CSC via counting sort, NPB=256 buckets (less binpass write fragmentation).
// ---------------------------------------------------------------------------

#define NPB      256     // nodes per bucket
#define NB_SHIFT 8
#define NBCAP    512     // max buckets (n <= 131072)

// ---------------- CSC build ----------------

__global__ void k_zero(int* __restrict__ p, int m) {
    int i = blockIdx.x * blockDim.x + threadIdx.x;
    if (i < m) p[i] = 0;
}

__global__ __launch_bounds__(256) void k_hist(const int* __restrict__ dst, int E,
                                              int* __restrict__ bcnt, int nb) {
    __shared__ int h[NBCAP];
    for (int i = threadIdx.x; i < nb; i += 256) h[i] = 0;
    __syncthreads();
    int stride = gridDim.x * 256;
    for (int e = blockIdx.x * 256 + threadIdx.x; e < E; e += stride)
        atomicAdd(&h[dst[e] >> NB_SHIFT], 1);
    __syncthreads();
    for (int i = threadIdx.x; i < nb; i += 256)
        if (h[i]) atomicAdd(&bcnt[i], h[i]);
}

__global__ __launch_bounds__(512) void k_scan_nb(const int* __restrict__ bcnt,
                                                 int* __restrict__ bbase,
                                                 int* __restrict__ bcur, int nb) {
    __shared__ int tmp[512];
    int t = threadIdx.x;
    int v = (t < nb) ? bcnt[t] : 0;
    tmp[t] = v;
    __syncthreads();
    for (int ofs = 1; ofs < 512; ofs <<= 1) {
        int u = (t >= ofs) ? tmp[t - ofs] : 0;
        __syncthreads();
        if (t >= ofs) tmp[t] += u;
        __syncthreads();
    }
    if (t < nb) {
        int ex = tmp[t] - v;
        bbase[t] = ex;
        bcur[t] = ex;
        if (t == nb - 1) bbase[nb] = tmp[t];
    }
}

// Partition edges into buckets as packed (src | ldst<<17), ldst < 256.
__global__ __launch_bounds__(256) void k_binpass(const int* __restrict__ src,
                                                 const int* __restrict__ dst,
                                                 int* __restrict__ bcur,
                                                 int* __restrict__ pairs,
                                                 int nb, int E) {
    __shared__ int lh[NBCAP];
    __shared__ int lbase[NBCAP];
    for (int i = threadIdx.x; i < nb; i += 256) lh[i] = 0;
    __syncthreads();
    int base = blockIdx.x * 4096;
    int pk[16], bb[16];
#pragma unroll
    for (int k = 0; k < 16; ++k) {
        int e = base + k * 256 + threadIdx.x;
        if (e < E) {
            int d = dst[e];
            int b = d >> NB_SHIFT;
            bb[k] = b;
            pk[k] = src[e] | ((d & (NPB - 1)) << 17);
            atomicAdd(&lh[b], 1);
        } else bb[k] = -1;
    }
    __syncthreads();
    for (int i = threadIdx.x; i < nb; i += 256) {
        int c = lh[i];
        lbase[i] = c ? atomicAdd(&bcur[i], c) : 0;
        lh[i] = 0;
    }
    __syncthreads();
#pragma unroll
    for (int k = 0; k < 16; ++k) {
        if (bb[k] >= 0) {
            int r = atomicAdd(&lh[bb[k]], 1);
            pairs[lbase[bb[k]] + r] = pk[k];
        }
    }
}

// One block per bucket: LDS deg count + scan -> off/dinv; cursor fill of csrc.
__global__ __launch_bounds__(256) void k_bucket_build(const int* __restrict__ pairs,
                                                      const int* __restrict__ bbase,
                                                      int* __restrict__ off,
                                                      int* __restrict__ csrc,
                                                      float* __restrict__ dinv,
                                                      int n, int nb) {
    __shared__ int deg[NPB], sc[NPB], cur[NPB];
    int t = threadIdx.x;
    int bid = blockIdx.x;
    int node0 = bid * NPB;
    int ebeg = bbase[bid], eend = bbase[bid + 1];
    deg[t] = 0;
    __syncthreads();
    for (int e = ebeg + t; e < eend; e += 256)
        atomicAdd(&deg[pairs[e] >> 17], 1);
    __syncthreads();
    sc[t] = deg[t];
    __syncthreads();
    for (int ofs = 1; ofs < NPB; ofs <<= 1) {
        int u = (t >= ofs) ? sc[t - ofs] : 0;
        __syncthreads();
        if (t >= ofs) sc[t] += u;
        __syncthreads();
    }
    {
        int ex = sc[t] - deg[t];
        cur[t] = ex;
        int node = node0 + t;
        if (node < n) {
            off[node] = ebeg + ex;
            dinv[node] = rsqrtf((float)(deg[t] + 1));
        }
    }
    if (t == 0 && bid == nb - 1) off[n] = eend;
    __syncthreads();
    for (int e = ebeg + t; e < eend; e += 256) {
        int pkv = pairs[e];
        int r = atomicAdd(&cur[pkv >> 17], 1);
        csrc[ebeg + r] = pkv & 0x1FFFF;
    }
}

// ---------------- helpers ----------------

union pk2 { __half2 h[2]; uint2 u; };
union pk4 { __half2 h[4]; uint4 u; };

#define F4ADD(a, b) { (a).x += (b).x; (a).y += (b).y; (a).z += (b).z; (a).w += (b).w; }

__device__ __forceinline__ void acc8f(float4& lo, float4& hi, uint4 u) {
    __half2 h0 = *(__half2*)&u.x, h1 = *(__half2*)&u.y;
    __half2 h2v = *(__half2*)&u.z, h3v = *(__half2*)&u.w;
    float2 f0 = __half22float2(h0), f1 = __half22float2(h1);
    float2 f2 = __half22float2(h2v), f3 = __half22float2(h3v);
    lo.x += f0.x; lo.y += f0.y; lo.z += f1.x; lo.w += f1.y;
    hi.x += f2.x; hi.y += f2.y; hi.z += f3.x; hi.w += f3.y;
}

__device__ __forceinline__ void redstep(float4& lo, float4& hi, int delta, bool act) {
    float4 rl, rh;
    rl.x = __shfl_down(lo.x, delta); rl.y = __shfl_down(lo.y, delta);
    rl.z = __shfl_down(lo.z, delta); rl.w = __shfl_down(lo.w, delta);
    rh.x = __shfl_down(hi.x, delta); rh.y = __shfl_down(hi.y, delta);
    rh.z = __shfl_down(hi.z, delta); rh.w = __shfl_down(hi.w, delta);
    if (act) { F4ADD(lo, rl); F4ADD(hi, rh); }
}

// ---------------- dense layers ----------------

// hs[n,64] = (x[n,128] @ W1[128,64]) * dinv[row], fp16 out.
__global__ __launch_bounds__(256) void k_gemm1_h(const float* __restrict__ x,
                                                 const float* __restrict__ W,
                                                 __half* __restrict__ h, int n,
                                                 const float* __restrict__ dinv) {
    __shared__ float Ws[128 * 64];
    __shared__ float xsT[128 * 64];
    const int tid = threadIdx.x;
    const int row0 = blockIdx.x * 64;
    {
        const float4* Wg = (const float4*)W;
        float4* Wl = (float4*)Ws;
#pragma unroll
        for (int t = 0; t < 8; ++t) Wl[tid + t * 256] = Wg[tid + t * 256];
    }
    {
        int r = tid & 63, g = tid >> 6;
        int row = row0 + r;
        const float4* xr = (const float4*)(x + (size_t)row * 128);
#pragma unroll
        for (int t = 0; t < 8; ++t) {
            int k0 = g * 32 + t * 4;
            float4 v = (row < n) ? xr[k0 >> 2] : make_float4(0.f, 0.f, 0.f, 0.f);
            xsT[(k0 + 0) * 64 + r] = v.x;
            xsT[(k0 + 1) * 64 + r] = v.y;
            xsT[(k0 + 2) * 64 + r] = v.z;
            xsT[(k0 + 3) * 64 + r] = v.w;
        }
    }
    __syncthreads();

    const int tc = tid & 15;
    const int rg = tid >> 4;
    float acc[4][4];
#pragma unroll
    for (int i = 0; i < 4; ++i)
#pragma unroll
        for (int j = 0; j < 4; ++j) acc[i][j] = 0.f;

#pragma unroll 4
    for (int k = 0; k < 128; ++k) {
        float4 a = *(const float4*)&xsT[k * 64 + rg * 4];
        float4 b = *(const float4*)&Ws[k * 64 + tc * 4];
        acc[0][0] += a.x * b.x; acc[0][1] += a.x * b.y; acc[0][2] += a.x * b.z; acc[0][3] += a.x * b.w;
        acc[1][0] += a.y * b.x; acc[1][1] += a.y * b.y; acc[1][2] += a.y * b.z; acc[1][3] += a.y * b.w;
        acc[2][0] += a.z * b.x; acc[2][1] += a.z * b.y; acc[2][2] += a.z * b.z; acc[2][3] += a.z * b.w;
        acc[3][0] += a.w * b.x; acc[3][1] += a.w * b.y; acc[3][2] += a.w * b.z; acc[3][3] += a.w * b.w;
    }

#pragma unroll
    for (int i = 0; i < 4; ++i) {
        int row = row0 + rg * 4 + i;
        if (row < n) {
            float dd = dinv[row];
            pk2 p;
            p.h[0] = __floats2half2_rn(acc[i][0] * dd, acc[i][1] * dd);
            p.h[1] = __floats2half2_rn(acc[i][2] * dd, acc[i][3] * dd);
            *(uint2*)&h[(size_t)row * 64 + tc * 4] = p.u;
        }
    }
}

// out[n,40] = g2[n,64] @ W2[64,40] + b2, fp32 out (g2 fp16, scales pre-applied).
__global__ __launch_bounds__(256) void k_gemm2_out(const __half* __restrict__ g2,
                                                   const float* __restrict__ W2,
                                                   const float* __restrict__ b2,
                                                   float* __restrict__ out, int n) {
    __shared__ float Ws[64 * 40];
    __shared__ float hsT[64 * 64];
    const int tid = threadIdx.x;
    const int row0 = blockIdx.x * 64;
    {
        const float4* Wg = (const float4*)W2;
        float4* Wl = (float4*)Ws;
        for (int i = tid; i < 640; i += 256) Wl[i] = Wg[i];
    }
    {
        int r = tid & 63, g = tid >> 6;
        int row = row0 + r;
        const __half* ar = g2 + (size_t)row * 64;
#pragma unroll
        for (int t = 0; t < 4; ++t) {
            int k0 = g * 16 + t * 4;
            float4 v = make_float4(0.f, 0.f, 0.f, 0.f);
            if (row < n) {
                uint2 u = *(const uint2*)(ar + k0);
                __half2 h0 = *(__half2*)&u.x, h1 = *(__half2*)&u.y;
                float2 f0 = __half22float2(h0), f1 = __half22float2(h1);
                v = make_float4(f0.x, f0.y, f1.x, f1.y);
            }
            hsT[(k0 + 0) * 64 + r] = v.x;
            hsT[(k0 + 1) * 64 + r] = v.y;
            hsT[(k0 + 2) * 64 + r] = v.z;
            hsT[(k0 + 3) * 64 + r] = v.w;
        }
    }
    __syncthreads();

    const int tc = tid & 15;
    const int rg = tid >> 4;
    if (tc < 10) {
        float acc[4][4];
#pragma unroll
        for (int i = 0; i < 4; ++i)
#pragma unroll
            for (int j = 0; j < 4; ++j) acc[i][j] = 0.f;

#pragma unroll 4
        for (int k = 0; k < 64; ++k) {
            float4 a = *(const float4*)&hsT[k * 64 + rg * 4];
            float4 b = *(const float4*)&Ws[k * 40 + tc * 4];
            acc[0][0] += a.x * b.x; acc[0][1] += a.x * b.y; acc[0][2] += a.x * b.z; acc[0][3] += a.x * b.w;
            acc[1][0] += a.y * b.x; acc[1][1] += a.y * b.y; acc[1][2] += a.y * b.z; acc[1][3] += a.y * b.w;
            acc[2][0] += a.z * b.x; acc[2][1] += a.z * b.y; acc[2][2] += a.z * b.z; acc[2][3] += a.z * b.w;
            acc[3][0] += a.w * b.x; acc[3][1] += a.w * b.y; acc[3][2] += a.w * b.z; acc[3][3] += a.w * b.w;
        }

        float4 bb = *(const float4*)(b2 + tc * 4);
#pragma unroll
        for (int i = 0; i < 4; ++i) {
            int row = row0 + rg * 4 + i;
            if (row < n)
                *(float4*)&out[(size_t)row * 40 + tc * 4] =
                    make_float4(acc[i][0] + bb.x, acc[i][1] + bb.y,
                                acc[i][2] + bb.z, acc[i][3] + bb.w);
        }
    }
}

// ---------------- quad-node gather (64-wide fp16 rows) ----------------

// mode 0 (layer1): o = relu((sum+self)*dd + bias) * dd   (emits r2)
// mode 1 (layer2): o = (sum+self)*dd                     (emits g2)
// Wave handles 4 adjacent nodes; 8 edge-groups x 8 feature-lanes; per
// iteration 4 unconditional independent row loads (clamped idx, masked acc).
__global__ __launch_bounds__(256) void k_gather4(const __half* __restrict__ feat,
                                                 const int* __restrict__ off,
                                                 const int* __restrict__ csrc,
                                                 const float* __restrict__ dinv,
                                                 const float* __restrict__ bias,
                                                 __half* __restrict__ outh,
                                                 int n, int E, int nwq, int mode) {
    int wid = (blockIdx.x * 256 + threadIdx.x) >> 6;
    int lane = threadIdx.x & 63;
    int g = lane >> 3, q = lane & 7;
    int Em1 = E - 1;
    for (int base = wid * 4; base < n; base += nwq * 4) {
        int b0, e0, b1, e1, b2_, e2, b3, e3;
        b0 = off[base]; e0 = off[base + 1];
        if (base + 1 < n) { b1 = off[base + 1]; e1 = off[base + 2]; } else { b1 = e1 = 0; }
        if (base + 2 < n) { b2_ = off[base + 2]; e2 = off[base + 3]; } else { b2_ = e2 = 0; }
        if (base + 3 < n) { b3 = off[base + 3]; e3 = off[base + 4]; } else { b3 = e3 = 0; }

        float4 A0l = make_float4(0.f, 0.f, 0.f, 0.f), A0h = A0l;
        float4 A1l = A0l, A1h = A0l, A2l = A0l, A2h = A0l, A3l = A0l, A3h = A0l;

        int j0 = b0, j1 = b1, j2 = b2_, j3 = b3;
        while ((j0 < e0) || (j1 < e1) || (j2 < e2) || (j3 < e3)) {
            bool v0 = j0 + g < e0, v1 = j1 + g < e1, v2 = j2 + g < e2, v3 = j3 + g < e3;
            int i0 = min(j0 + g, Em1), i1 = min(j1 + g, Em1);
            int i2 = min(j2 + g, Em1), i3 = min(j3 + g, Em1);
            int s0 = csrc[i0], s1 = csrc[i1], s2 = csrc[i2], s3 = csrc[i3];
            uint4 u0 = *(const uint4*)(feat + ((size_t)s0 << 6) + (q << 3));
            uint4 u1 = *(const uint4*)(feat + ((size_t)s1 << 6) + (q << 3));
            uint4 u2 = *(const uint4*)(feat + ((size_t)s2 << 6) + (q << 3));
            uint4 u3 = *(const uint4*)(feat + ((size_t)s3 << 6) + (q << 3));
            if (v0) acc8f(A0l, A0h, u0);
            if (v1) acc8f(A1l, A1h, u1);
            if (v2) acc8f(A2l, A2h, u2);
            if (v3) acc8f(A3l, A3h, u3);
            j0 += 8; j1 += 8; j2 += 8; j3 += 8;
        }

        redstep(A0l, A0h, 32, lane < 32);
        redstep(A0l, A0h, 16, lane < 16);
        redstep(A0l, A0h, 8,  lane < 8);
        redstep(A1l, A1h, 32, lane < 32);
        redstep(A1l, A1h, 16, lane < 16);
        redstep(A1l, A1h, 8,  lane < 8);
        redstep(A2l, A2h, 32, lane < 32);
        redstep(A2l, A2h, 16, lane < 16);
        redstep(A2l, A2h, 8,  lane < 8);
        redstep(A3l, A3h, 32, lane < 32);
        redstep(A3l, A3h, 16, lane < 16);
        redstep(A3l, A3h, 8,  lane < 8);

        if (lane < 8) {
            float4 blo = make_float4(0.f, 0.f, 0.f, 0.f), bhi = blo;
            if (mode == 0) {
                blo = *(const float4*)(bias + q * 8);
                bhi = *(const float4*)(bias + q * 8 + 4);
            }
#define EPI(K, AL, AH)                                                          \
            {                                                                   \
                int node = base + K;                                            \
                if (node < n) {                                                 \
                    float dd = dinv[node];                                      \
                    uint4 us = *(const uint4*)(feat + ((size_t)node << 6) + (q << 3)); \
                    float4 sl = make_float4(0.f, 0.f, 0.f, 0.f), sh = sl;       \
                    acc8f(sl, sh, us);                                          \
                    float f0 = (AL.x + sl.x) * dd + blo.x;                      \
                    float f1 = (AL.y + sl.y) * dd + blo.y;                      \
                    float f2 = (AL.z + sl.z) * dd + blo.z;                      \
                    float f3 = (AL.w + sl.w) * dd + blo.w;                      \
                    float f4 = (AH.x + sh.x) * dd + bhi.x;                      \
                    float f5 = (AH.y + sh.y) * dd + bhi.y;                      \
                    float f6 = (AH.z + sh.z) * dd + bhi.z;                      \
                    float f7 = (AH.w + sh.w) * dd + bhi.w;                      \
                    if (mode == 0) {                                            \
                        f0 = (f0 > 0.f ? f0 : 0.f) * dd;                        \
                        f1 = (f1 > 0.f ? f1 : 0.f) * dd;                        \
                        f2 = (f2 > 0.f ? f2 : 0.f) * dd;                        \
                        f3 = (f3 > 0.f ? f3 : 0.f) * dd;                        \
                        f4 = (f4 > 0.f ? f4 : 0.f) * dd;                        \
                        f5 = (f5 > 0.f ? f5 : 0.f) * dd;                        \
                        f6 = (f6 > 0.f ? f6 : 0.f) * dd;                        \
                        f7 = (f7 > 0.f ? f7 : 0.f) * dd;                        \
                    }                                                           \
                    pk4 p;                                                      \
                    p.h[0] = __floats2half2_rn(f0, f1);                         \
                    p.h[1] = __floats2half2_rn(f2, f3);                         \
                    p.h[2] = __floats2half2_rn(f4, f5);                         \
                    p.h[3] = __floats2half2_rn(f6, f7);                         \
                    *(uint4*)&outh[((size_t)node << 6) + (q << 3)] = p.u;       \
                }                                                               \
            }
            EPI(0, A0l, A0h)
            EPI(1, A1l, A1h)
            EPI(2, A2l, A2h)
            EPI(3, A3l, A3h)
#undef EPI
        }
    }
}

// ---------------- fallback atomic-scatter path (fp32, proven) ----------------

__global__ void k_init_deg(float* __restrict__ deg, int n) {
    int i = blockIdx.x * blockDim.x + threadIdx.x;
    if (i < n) deg[i] = 1.0f;
}

__global__ void k_deg(const int* __restrict__ dst, int E, float* __restrict__ deg) {
    int i = blockIdx.x * blockDim.x + threadIdx.x;
    if (i < E) atomicAdd(&deg[dst[i]], 1.0f);
}

__global__ void k_rsqrt(float* __restrict__ deg, int n) {
    int i = blockIdx.x * blockDim.x + threadIdx.x;
    if (i < n) deg[i] = rsqrtf(deg[i]);
}

__global__ __launch_bounds__(256) void k_gemm1_f(const float* __restrict__ x,
                                                 const float* __restrict__ W,
                                                 float* __restrict__ h, int n) {
    __shared__ float Ws[128 * 64];
    __shared__ float xsT[128 * 64];
    const int tid = threadIdx.x;
    const int row0 = blockIdx.x * 64;
    {
        const float4* Wg = (const float4*)W;
        float4* Wl = (float4*)Ws;
#pragma unroll
        for (int t = 0; t < 8; ++t) Wl[tid + t * 256] = Wg[tid + t * 256];
    }
    {
        int r = tid & 63, g = tid >> 6;
        int row = row0 + r;
        const float4* xr = (const float4*)(x + (size_t)row * 128);
#pragma unroll
        for (int t = 0; t < 8; ++t) {
            int k0 = g * 32 + t * 4;
            float4 v = (row < n) ? xr[k0 >> 2] : make_float4(0.f, 0.f, 0.f, 0.f);
            xsT[(k0 + 0) * 64 + r] = v.x;
            xsT[(k0 + 1) * 64 + r] = v.y;
            xsT[(k0 + 2) * 64 + r] = v.z;
            xsT[(k0 + 3) * 64 + r] = v.w;
        }
    }
    __syncthreads();
    const int tc = tid & 15;
    const int rg = tid >> 4;
    float acc[4][4];
#pragma unroll
    for (int i = 0; i < 4; ++i)
#pragma unroll
        for (int j = 0; j < 4; ++j) acc[i][j] = 0.f;
#pragma unroll 4
    for (int k = 0; k < 128; ++k) {
        float4 a = *(const float4*)&xsT[k * 64 + rg * 4];
        float4 b = *(const float4*)&Ws[k * 64 + tc * 4];
        acc[0][0] += a.x * b.x; acc[0][1] += a.x * b.y; acc[0][2] += a.x * b.z; acc[0][3] += a.x * b.w;
        acc[1][0] += a.y * b.x; acc[1][1] += a.y * b.y; acc[1][2] += a.y * b.z; acc[1][3] += a.y * b.w;
        acc[2][0] += a.z * b.x; acc[2][1] += a.z * b.y; acc[2][2] += a.z * b.z; acc[2][3] += a.z * b.w;
        acc[3][0] += a.w * b.x; acc[3][1] += a.w * b.y; acc[3][2] += a.w * b.z; acc[3][3] += a.w * b.w;
    }
#pragma unroll
    for (int i = 0; i < 4; ++i) {
        int row = row0 + rg * 4 + i;
        if (row < n)
            *(float4*)&h[(size_t)row * 64 + tc * 4] =
                make_float4(acc[i][0], acc[i][1], acc[i][2], acc[i][3]);
    }
}

__global__ __launch_bounds__(256) void k_gemm2_f(const float* __restrict__ agg,
                                                 const float* __restrict__ W2,
                                                 float* __restrict__ h2, int n) {
    __shared__ float Ws[64 * 40];
    __shared__ float hsT[64 * 64];
    const int tid = threadIdx.x;
    const int row0 = blockIdx.x * 64;
    {
        const float4* Wg = (const float4*)W2;
        float4* Wl = (float4*)Ws;
        for (int i = tid; i < 640; i += 256) Wl[i] = Wg[i];
    }
    {
        int r = tid & 63, g = tid >> 6;
        int row = row0 + r;
        const float4* ar = (const float4*)(agg + (size_t)row * 64);
#pragma unroll
        for (int t = 0; t < 4; ++t) {
            int k0 = g * 16 + t * 4;
            float4 v = (row < n) ? ar[k0 >> 2] : make_float4(0.f, 0.f, 0.f, 0.f);
            hsT[(k0 + 0) * 64 + r] = v.x > 0.f ? v.x : 0.f;
            hsT[(k0 + 1) * 64 + r] = v.y > 0.f ? v.y : 0.f;
            hsT[(k0 + 2) * 64 + r] = v.z > 0.f ? v.z : 0.f;
            hsT[(k0 + 3) * 64 + r] = v.w > 0.f ? v.w : 0.f;
        }
    }
    __syncthreads();
    const int tc = tid & 15;
    const int rg = tid >> 4;
    if (tc < 10) {
        float acc[4][4];
#pragma unroll
        for (int i = 0; i < 4; ++i)
#pragma unroll
            for (int j = 0; j < 4; ++j) acc[i][j] = 0.f;
#pragma unroll 4
        for (int k = 0; k < 64; ++k) {
            float4 a = *(const float4*)&hsT[k * 64 + rg * 4];
            float4 b = *(const float4*)&Ws[k * 40 + tc * 4];
            acc[0][0] += a.x * b.x; acc[0][1] += a.x * b.y; acc[0][2] += a.x * b.z; acc[0][3] += a.x * b.w;
            acc[1][0] += a.y * b.x; acc[1][1] += a.y * b.y; acc[1][2] += a.y * b.z; acc[1][3] += a.y * b.w;
            acc[2][0] += a.z * b.x; acc[2][1] += a.z * b.y; acc[2][2] += a.z * b.z; acc[2][3] += a.z * b.w;
            acc[3][0] += a.w * b.x; acc[3][1] += a.w * b.y; acc[3][2] += a.w * b.z; acc[3][3] += a.w * b.w;
        }
#pragma unroll
        for (int i = 0; i < 4; ++i) {
            int row = row0 + rg * 4 + i;
            if (row < n)
                *(float4*)&h2[(size_t)row * 40 + tc * 4] =
                    make_float4(acc[i][0], acc[i][1], acc[i][2], acc[i][3]);
        }
    }
}

__global__ void k_init_agg1(const float* __restrict__ h, const float* __restrict__ dinv,
                            const float* __restrict__ b1, float* __restrict__ agg, int n) {
    int idx = blockIdx.x * blockDim.x + threadIdx.x;
    if (idx < n * 64) {
        int i = idx >> 6, f = idx & 63;
        float d = dinv[i];
        agg[idx] = h[idx] * d * d + b1[f];
    }
}

__global__ __launch_bounds__(256) void k_scatter1(const float* __restrict__ h,
                                                  const int* __restrict__ src,
                                                  const int* __restrict__ dst,
                                                  const float* __restrict__ dinv,
                                                  float* __restrict__ agg, int E) {
    int e = blockIdx.x * 4 + (threadIdx.x >> 6);
    if (e >= E) return;
    int f = threadIdx.x & 63;
    int s = src[e], d = dst[e];
    float w = dinv[s] * dinv[d];
    atomicAdd(&agg[d * 64 + f], h[s * 64 + f] * w);
}

__global__ void k_init_out(const float* __restrict__ h2, const float* __restrict__ dinv,
                           const float* __restrict__ b2, float* __restrict__ out, int n) {
    int idx = blockIdx.x * blockDim.x + threadIdx.x;
    if (idx < n * 40) {
        int i = idx / 40;
        int f = idx - i * 40;
        float d = dinv[i];
        out[idx] = h2[idx] * d * d + b2[f];
    }
}

__global__ __launch_bounds__(256) void k_scatter2(const float* __restrict__ h2,
                                                  const int* __restrict__ src,
                                                  const int* __restrict__ dst,
                                                  const float* __restrict__ dinv,
                                                  float* __restrict__ out, int E) {
    int idx = blockIdx.x * blockDim.x + threadIdx.x;
    int total = E * 40;
    if (idx >= total) return;
    int e = idx / 40;
    int f = idx - e * 40;
    int s = src[e], d = dst[e];
    float w = dinv[s] * dinv[d];
    atomicAdd(&out[d * 40 + f], h2[s * 40 + f] * w);
}

extern "C" void kernel_launch(void* const* d_in, const int* in_sizes, int n_in,
                              void* d_out, int out_size, void* d_ws, size_t ws_size,
                              hipStream_t stream) {
    const float* x  = (const float*)d_in[0];
    const int*   ei = (const int*)d_in[1];
    const float* W1 = (const float*)d_in[2];
    const float* b1 = (const float*)d_in[3];
    const float* W2 = (const float*)d_in[4];
    const float* b2 = (const float*)d_in[5];
    float* out = (float*)d_out;

    const int n = in_sizes[0] / 128;   // 100000
    const int E = in_sizes[1] / 2;     // 1600000
    const int* src = ei;
    const int* dst = ei + E;

    char* ws = (char*)d_ws;
    const size_t MB = 1 << 20;
    float*  dinv   = (float*)(ws);                       // n floats
    int*    off    = (int*)  (ws + 512 * 1024);          // n+1 ints
    int*    bcnt   = (int*)  (ws + 1 * MB);              // NBCAP ints
    int*    bbase  = (int*)  (ws + 1 * MB + 8 * 1024);   // NBCAP+1 ints
    int*    bcur   = (int*)  (ws + 1 * MB + 16 * 1024);  // NBCAP ints
    __half* hs_h   = (__half*)(ws + 2 * MB);             // n*64 halves (12.8MB)
    __half* r2_h   = (__half*)(ws + 15 * MB);            // n*64 halves (12.8MB)
    __half* g2_h   = hs_h;                               // reuse (hs dead after gather1)
    int*    pairs  = (int*)  (ws + 28 * MB);             // E ints
    int*    csrc   = (int*)  (ws + 35 * MB);             // E ints
    size_t needed_fast = 35 * MB + (size_t)E * 4;

    const int nb = (n + NPB - 1) / NPB;

    if (ws_size >= needed_fast && nb <= NBCAP && n <= (1 << 17) && E >= 8) {
        // ---- CSC build via counting sort ----
        k_zero<<<(nb + 255) / 256, 256, 0, stream>>>(bcnt, nb);
        k_hist<<<512, 256, 0, stream>>>(dst, E, bcnt, nb);
        k_scan_nb<<<1, 512, 0, stream>>>(bcnt, bbase, bcur, nb);
        k_binpass<<<(E + 4095) / 4096, 256, 0, stream>>>(src, dst, bcur, pairs, nb, E);
        k_bucket_build<<<nb, 256, 0, stream>>>(pairs, bbase, off, csrc, dinv, n, nb);

        const int GB = 2048;                 // persistent gather blocks
        const int NW = GB * 4;               // waves

        // ---- layer 1: hs = (x@W1)*dinv; r2 = relu(Ahat-agg + b1)*dinv ----
        k_gemm1_h<<<(n + 63) / 64, 256, 0, stream>>>(x, W1, hs_h, n, dinv);
        k_gather4<<<GB, 256, 0, stream>>>(hs_h, off, csrc, dinv, b1, r2_h, n, E, NW, 0);

        // ---- layer 2: g2 = Ahat-agg(r2); out = g2 @ W2 + b2 ----
        k_gather4<<<GB, 256, 0, stream>>>(r2_h, off, csrc, dinv, nullptr, g2_h, n, E, NW, 1);
        k_gemm2_out<<<(n + 63) / 64, 256, 0, stream>>>(g2_h, W2, b2, out, n);
    } else {
        // ---- fallback: fp32 atomic scatter path ----
        float* hlin = (float*)(ws + 2 * MB);
        float* agg1 = (float*)(ws + 28 * MB);
        k_init_deg<<<(n + 255) / 256, 256, 0, stream>>>(dinv, n);
        k_deg<<<(E + 255) / 256, 256, 0, stream>>>(dst, E, dinv);
        k_rsqrt<<<(n + 255) / 256, 256, 0, stream>>>(dinv, n);
        k_gemm1_f<<<(n + 63) / 64, 256, 0, stream>>>(x, W1, hlin, n);
        k_init_agg1<<<(n * 64 + 255) / 256, 256, 0, stream>>>(hlin, dinv, b1, agg1, n);
        k_scatter1<<<(E + 3) / 4, 256, 0, stream>>>(hlin, src, dst, dinv, agg1, E);
        k_gemm2_f<<<(n + 63) / 64, 256, 0, stream>>>(agg1, W2, hlin, n);
        k_init_out<<<(n * 40 + 255) / 256, 256, 0, stream>>>(hlin, dinv, b2, out, n);
        int total2 = E * 40;
        k_scatter2<<<(total2 + 255) / 256, 256, 0, stream>>>(hlin, src, dst, dinv, out, E);
    }
}

// Round 9
// 196.007 us; speedup vs baseline: 1.1491x; 1.1491x over previous
//
#include <hip/hip_runtime.h>
#include <hip/hip_fp16.h>

// ---------------------------------------------------------------------------
// GCN 2-layer forward: out = A_hat @ relu(A_hat @ (x@W1) + b1) @ W2 + b2
// A_hat = D^-1/2 (A + I) D^-1/2.
// Layer-2 algebra swap: out = (A_hat @ relu(agg1)) @ W2 + b2, so BOTH gathers
// run on 64-wide 128B-aligned fp16 rows. Gather = round-7 proven single-node
// wave structure (8 edge-groups x 8 lanes, uint4 loads, 2-deep unroll).
// CSC via counting sort (round-7 proven, NPB=128).
// ---------------------------------------------------------------------------

#define NPB   128     // nodes per coarse bucket
#define NBCAP 1024    // max buckets supported by fast path

// ---------------- CSC build ----------------

__global__ void k_zero(int* __restrict__ p, int m) {
    int i = blockIdx.x * blockDim.x + threadIdx.x;
    if (i < m) p[i] = 0;
}

__global__ __launch_bounds__(256) void k_hist(const int* __restrict__ dst, int E,
                                              int* __restrict__ bcnt, int nb) {
    __shared__ int h[NBCAP];
    for (int i = threadIdx.x; i < nb; i += 256) h[i] = 0;
    __syncthreads();
    int stride = gridDim.x * 256;
    for (int e = blockIdx.x * 256 + threadIdx.x; e < E; e += stride)
        atomicAdd(&h[dst[e] >> 7], 1);
    __syncthreads();
    for (int i = threadIdx.x; i < nb; i += 256)
        if (h[i]) atomicAdd(&bcnt[i], h[i]);
}

__global__ __launch_bounds__(1024) void k_scan_nb(const int* __restrict__ bcnt,
                                                  int* __restrict__ bbase,
                                                  int* __restrict__ bcur, int nb) {
    __shared__ int tmp[NBCAP];
    int t = threadIdx.x;
    int v = (t < nb) ? bcnt[t] : 0;
    tmp[t] = v;
    __syncthreads();
    for (int ofs = 1; ofs < NBCAP; ofs <<= 1) {
        int u = (t >= ofs) ? tmp[t - ofs] : 0;
        __syncthreads();
        if (t >= ofs) tmp[t] += u;
        __syncthreads();
    }
    if (t < nb) {
        int ex = tmp[t] - v;
        bbase[t] = ex;
        bcur[t] = ex;
        if (t == nb - 1) bbase[nb] = tmp[t];
    }
}

__global__ __launch_bounds__(256) void k_binpass(const int* __restrict__ src,
                                                 const int* __restrict__ dst,
                                                 int* __restrict__ bcur,
                                                 int* __restrict__ pairs,
                                                 int nb, int E) {
    __shared__ int lh[NBCAP];
    __shared__ int lbase[NBCAP];
    for (int i = threadIdx.x; i < nb; i += 256) lh[i] = 0;
    __syncthreads();
    int base = blockIdx.x * 4096;
    int pk[16], bb[16];
#pragma unroll
    for (int k = 0; k < 16; ++k) {
        int e = base + k * 256 + threadIdx.x;
        if (e < E) {
            int d = dst[e];
            int b = d >> 7;
            bb[k] = b;
            pk[k] = src[e] | ((d & (NPB - 1)) << 17);
            atomicAdd(&lh[b], 1);
        } else bb[k] = -1;
    }
    __syncthreads();
    for (int i = threadIdx.x; i < nb; i += 256) {
        int c = lh[i];
        lbase[i] = c ? atomicAdd(&bcur[i], c) : 0;
        lh[i] = 0;
    }
    __syncthreads();
#pragma unroll
    for (int k = 0; k < 16; ++k) {
        if (bb[k] >= 0) {
            int r = atomicAdd(&lh[bb[k]], 1);
            pairs[lbase[bb[k]] + r] = pk[k];
        }
    }
}

__global__ __launch_bounds__(256) void k_bucket_build(const int* __restrict__ pairs,
                                                      const int* __restrict__ bbase,
                                                      int* __restrict__ off,
                                                      int* __restrict__ csrc,
                                                      float* __restrict__ dinv,
                                                      int n, int nb) {
    __shared__ int deg[NPB], sc[NPB], cur[NPB];
    int t = threadIdx.x;
    int bid = blockIdx.x;
    int node0 = bid * NPB;
    int ebeg = bbase[bid], eend = bbase[bid + 1];
    if (t < NPB) deg[t] = 0;
    __syncthreads();
    for (int e = ebeg + t; e < eend; e += 256)
        atomicAdd(&deg[pairs[e] >> 17], 1);
    __syncthreads();
    if (t < NPB) sc[t] = deg[t];
    __syncthreads();
    for (int ofs = 1; ofs < NPB; ofs <<= 1) {
        int u = (t < NPB && t >= ofs) ? sc[t - ofs] : 0;
        __syncthreads();
        if (t < NPB && t >= ofs) sc[t] += u;
        __syncthreads();
    }
    if (t < NPB) {
        int ex = sc[t] - deg[t];
        cur[t] = ex;
        int node = node0 + t;
        if (node < n) {
            off[node] = ebeg + ex;
            dinv[node] = rsqrtf((float)(deg[t] + 1));
        }
    }
    if (t == 0 && bid == nb - 1) off[n] = eend;
    __syncthreads();
    for (int e = ebeg + t; e < eend; e += 256) {
        int pkv = pairs[e];
        int r = atomicAdd(&cur[pkv >> 17], 1);
        csrc[ebeg + r] = pkv & 0x1FFFF;
    }
}

// ---------------- helpers ----------------

union pk2 { __half2 h[2]; uint2 u; };
union pk4 { __half2 h[4]; uint4 u; };

#define F4ADD(a, b) { (a).x += (b).x; (a).y += (b).y; (a).z += (b).z; (a).w += (b).w; }

__device__ __forceinline__ void acc8f(float4& lo, float4& hi, uint4 u) {
    __half2 h0 = *(__half2*)&u.x, h1 = *(__half2*)&u.y;
    __half2 h2v = *(__half2*)&u.z, h3v = *(__half2*)&u.w;
    float2 f0 = __half22float2(h0), f1 = __half22float2(h1);
    float2 f2 = __half22float2(h2v), f3 = __half22float2(h3v);
    lo.x += f0.x; lo.y += f0.y; lo.z += f1.x; lo.w += f1.y;
    hi.x += f2.x; hi.y += f2.y; hi.z += f3.x; hi.w += f3.y;
}

__device__ __forceinline__ void redstep(float4& lo, float4& hi, int delta, bool act) {
    float4 rl, rh;
    rl.x = __shfl_down(lo.x, delta); rl.y = __shfl_down(lo.y, delta);
    rl.z = __shfl_down(lo.z, delta); rl.w = __shfl_down(lo.w, delta);
    rh.x = __shfl_down(hi.x, delta); rh.y = __shfl_down(hi.y, delta);
    rh.z = __shfl_down(hi.z, delta); rh.w = __shfl_down(hi.w, delta);
    if (act) { F4ADD(lo, rl); F4ADD(hi, rh); }
}

// ---------------- dense layers ----------------

// hs[n,64] = (x[n,128] @ W1[128,64]) * dinv[row], fp16 out.
__global__ __launch_bounds__(256) void k_gemm1_h(const float* __restrict__ x,
                                                 const float* __restrict__ W,
                                                 __half* __restrict__ h, int n,
                                                 const float* __restrict__ dinv) {
    __shared__ float Ws[128 * 64];
    __shared__ float xsT[128 * 64];
    const int tid = threadIdx.x;
    const int row0 = blockIdx.x * 64;
    {
        const float4* Wg = (const float4*)W;
        float4* Wl = (float4*)Ws;
#pragma unroll
        for (int t = 0; t < 8; ++t) Wl[tid + t * 256] = Wg[tid + t * 256];
    }
    {
        int r = tid & 63, g = tid >> 6;
        int row = row0 + r;
        const float4* xr = (const float4*)(x + (size_t)row * 128);
#pragma unroll
        for (int t = 0; t < 8; ++t) {
            int k0 = g * 32 + t * 4;
            float4 v = (row < n) ? xr[k0 >> 2] : make_float4(0.f, 0.f, 0.f, 0.f);
            xsT[(k0 + 0) * 64 + r] = v.x;
            xsT[(k0 + 1) * 64 + r] = v.y;
            xsT[(k0 + 2) * 64 + r] = v.z;
            xsT[(k0 + 3) * 64 + r] = v.w;
        }
    }
    __syncthreads();

    const int tc = tid & 15;
    const int rg = tid >> 4;
    float acc[4][4];
#pragma unroll
    for (int i = 0; i < 4; ++i)
#pragma unroll
        for (int j = 0; j < 4; ++j) acc[i][j] = 0.f;

#pragma unroll 4
    for (int k = 0; k < 128; ++k) {
        float4 a = *(const float4*)&xsT[k * 64 + rg * 4];
        float4 b = *(const float4*)&Ws[k * 64 + tc * 4];
        acc[0][0] += a.x * b.x; acc[0][1] += a.x * b.y; acc[0][2] += a.x * b.z; acc[0][3] += a.x * b.w;
        acc[1][0] += a.y * b.x; acc[1][1] += a.y * b.y; acc[1][2] += a.y * b.z; acc[1][3] += a.y * b.w;
        acc[2][0] += a.z * b.x; acc[2][1] += a.z * b.y; acc[2][2] += a.z * b.z; acc[2][3] += a.z * b.w;
        acc[3][0] += a.w * b.x; acc[3][1] += a.w * b.y; acc[3][2] += a.w * b.z; acc[3][3] += a.w * b.w;
    }

#pragma unroll
    for (int i = 0; i < 4; ++i) {
        int row = row0 + rg * 4 + i;
        if (row < n) {
            float dd = dinv[row];
            pk2 p;
            p.h[0] = __floats2half2_rn(acc[i][0] * dd, acc[i][1] * dd);
            p.h[1] = __floats2half2_rn(acc[i][2] * dd, acc[i][3] * dd);
            *(uint2*)&h[(size_t)row * 64 + tc * 4] = p.u;
        }
    }
}

// out[n,40] = g2[n,64] @ W2[64,40] + b2, fp32 out (g2 fp16, scales pre-applied).
__global__ __launch_bounds__(256) void k_gemm2_out(const __half* __restrict__ g2,
                                                   const float* __restrict__ W2,
                                                   const float* __restrict__ b2,
                                                   float* __restrict__ out, int n) {
    __shared__ float Ws[64 * 40];
    __shared__ float hsT[64 * 64];
    const int tid = threadIdx.x;
    const int row0 = blockIdx.x * 64;
    {
        const float4* Wg = (const float4*)W2;
        float4* Wl = (float4*)Ws;
        for (int i = tid; i < 640; i += 256) Wl[i] = Wg[i];
    }
    {
        int r = tid & 63, g = tid >> 6;
        int row = row0 + r;
        const __half* ar = g2 + (size_t)row * 64;
#pragma unroll
        for (int t = 0; t < 4; ++t) {
            int k0 = g * 16 + t * 4;
            float4 v = make_float4(0.f, 0.f, 0.f, 0.f);
            if (row < n) {
                uint2 u = *(const uint2*)(ar + k0);
                __half2 h0 = *(__half2*)&u.x, h1 = *(__half2*)&u.y;
                float2 f0 = __half22float2(h0), f1 = __half22float2(h1);
                v = make_float4(f0.x, f0.y, f1.x, f1.y);
            }
            hsT[(k0 + 0) * 64 + r] = v.x;
            hsT[(k0 + 1) * 64 + r] = v.y;
            hsT[(k0 + 2) * 64 + r] = v.z;
            hsT[(k0 + 3) * 64 + r] = v.w;
        }
    }
    __syncthreads();

    const int tc = tid & 15;
    const int rg = tid >> 4;
    if (tc < 10) {
        float acc[4][4];
#pragma unroll
        for (int i = 0; i < 4; ++i)
#pragma unroll
            for (int j = 0; j < 4; ++j) acc[i][j] = 0.f;

#pragma unroll 4
        for (int k = 0; k < 64; ++k) {
            float4 a = *(const float4*)&hsT[k * 64 + rg * 4];
            float4 b = *(const float4*)&Ws[k * 40 + tc * 4];
            acc[0][0] += a.x * b.x; acc[0][1] += a.x * b.y; acc[0][2] += a.x * b.z; acc[0][3] += a.x * b.w;
            acc[1][0] += a.y * b.x; acc[1][1] += a.y * b.y; acc[1][2] += a.y * b.z; acc[1][3] += a.y * b.w;
            acc[2][0] += a.z * b.x; acc[2][1] += a.z * b.y; acc[2][2] += a.z * b.z; acc[2][3] += a.z * b.w;
            acc[3][0] += a.w * b.x; acc[3][1] += a.w * b.y; acc[3][2] += a.w * b.z; acc[3][3] += a.w * b.w;
        }

        float4 bb = *(const float4*)(b2 + tc * 4);
#pragma unroll
        for (int i = 0; i < 4; ++i) {
            int row = row0 + rg * 4 + i;
            if (row < n)
                *(float4*)&out[(size_t)row * 40 + tc * 4] =
                    make_float4(acc[i][0] + bb.x, acc[i][1] + bb.y,
                                acc[i][2] + bb.z, acc[i][3] + bb.w);
        }
    }
}

// ---------------- gather: single-node waves, 64-wide fp16 rows ----------------

// mode 0 (layer1): o = relu((sum+self)*dd + bias) * dd   (emits r2)
// mode 1 (layer2): o = (sum+self)*dd                     (emits g2)
// Wave per node (grid-stride); 8 edge-groups x 8 lanes; lane loads uint4
// (8 fp16 feats); 16 edges in flight; 3-step guarded shfl reduce.
__global__ __launch_bounds__(256) void k_gather_h(const __half* __restrict__ feat,
                                                  const int* __restrict__ off,
                                                  const int* __restrict__ csrc,
                                                  const float* __restrict__ dinv,
                                                  const float* __restrict__ bias,
                                                  __half* __restrict__ outh,
                                                  int n, int nwaves, int mode) {
    int wid = (blockIdx.x * 256 + threadIdx.x) >> 6;
    int lane = threadIdx.x & 63;
    int g = lane >> 3, q = lane & 7;       // edge group / feature quad
    for (int node = wid; node < n; node += nwaves) {
        int beg = off[node], end = off[node + 1];
        float4 a0 = make_float4(0.f, 0.f, 0.f, 0.f);
        float4 a1 = make_float4(0.f, 0.f, 0.f, 0.f);
        float4 c0 = make_float4(0.f, 0.f, 0.f, 0.f);
        float4 c1 = make_float4(0.f, 0.f, 0.f, 0.f);
        int j = beg;
        for (; j + 16 <= end; j += 16) {
            int s0 = csrc[j + g];
            int s1 = csrc[j + 8 + g];
            uint4 u0 = *(const uint4*)(feat + ((size_t)s0 << 6) + (q << 3));
            uint4 u1 = *(const uint4*)(feat + ((size_t)s1 << 6) + (q << 3));
            acc8f(a0, a1, u0);
            acc8f(c0, c1, u1);
        }
        for (; j + 8 <= end; j += 8) {
            int s0 = csrc[j + g];
            uint4 u0 = *(const uint4*)(feat + ((size_t)s0 << 6) + (q << 3));
            acc8f(a0, a1, u0);
        }
        if (j + g < end) {
            int s0 = csrc[j + g];
            uint4 u0 = *(const uint4*)(feat + ((size_t)s0 << 6) + (q << 3));
            acc8f(a0, a1, u0);
        }
        F4ADD(a0, c0); F4ADD(a1, c1);
        redstep(a0, a1, 32, lane < 32);
        redstep(a0, a1, 16, lane < 16);
        redstep(a0, a1, 8,  lane < 8);
        if (lane < 8) {
            float dd = dinv[node];
            uint4 us = *(const uint4*)(feat + ((size_t)node << 6) + (q << 3));
            float4 slo = make_float4(0.f, 0.f, 0.f, 0.f);
            float4 shi = make_float4(0.f, 0.f, 0.f, 0.f);
            acc8f(slo, shi, us);
            float f0 = (a0.x + slo.x) * dd;
            float f1 = (a0.y + slo.y) * dd;
            float f2 = (a0.z + slo.z) * dd;
            float f3 = (a0.w + slo.w) * dd;
            float f4 = (a1.x + shi.x) * dd;
            float f5 = (a1.y + shi.y) * dd;
            float f6 = (a1.z + shi.z) * dd;
            float f7 = (a1.w + shi.w) * dd;
            if (mode == 0) {
                float4 blo = *(const float4*)(bias + q * 8);
                float4 bhi = *(const float4*)(bias + q * 8 + 4);
                f0 += blo.x; f1 += blo.y; f2 += blo.z; f3 += blo.w;
                f4 += bhi.x; f5 += bhi.y; f6 += bhi.z; f7 += bhi.w;
                f0 = (f0 > 0.f ? f0 : 0.f) * dd;
                f1 = (f1 > 0.f ? f1 : 0.f) * dd;
                f2 = (f2 > 0.f ? f2 : 0.f) * dd;
                f3 = (f3 > 0.f ? f3 : 0.f) * dd;
                f4 = (f4 > 0.f ? f4 : 0.f) * dd;
                f5 = (f5 > 0.f ? f5 : 0.f) * dd;
                f6 = (f6 > 0.f ? f6 : 0.f) * dd;
                f7 = (f7 > 0.f ? f7 : 0.f) * dd;
            }
            pk4 p;
            p.h[0] = __floats2half2_rn(f0, f1);
            p.h[1] = __floats2half2_rn(f2, f3);
            p.h[2] = __floats2half2_rn(f4, f5);
            p.h[3] = __floats2half2_rn(f6, f7);
            *(uint4*)&outh[((size_t)node << 6) + (q << 3)] = p.u;
        }
    }
}

// ---------------- fallback atomic-scatter path (fp32, proven) ----------------

__global__ void k_init_deg(float* __restrict__ deg, int n) {
    int i = blockIdx.x * blockDim.x + threadIdx.x;
    if (i < n) deg[i] = 1.0f;
}

__global__ void k_deg(const int* __restrict__ dst, int E, float* __restrict__ deg) {
    int i = blockIdx.x * blockDim.x + threadIdx.x;
    if (i < E) atomicAdd(&deg[dst[i]], 1.0f);
}

__global__ void k_rsqrt(float* __restrict__ deg, int n) {
    int i = blockIdx.x * blockDim.x + threadIdx.x;
    if (i < n) deg[i] = rsqrtf(deg[i]);
}

__global__ __launch_bounds__(256) void k_gemm1_f(const float* __restrict__ x,
                                                 const float* __restrict__ W,
                                                 float* __restrict__ h, int n) {
    __shared__ float Ws[128 * 64];
    __shared__ float xsT[128 * 64];
    const int tid = threadIdx.x;
    const int row0 = blockIdx.x * 64;
    {
        const float4* Wg = (const float4*)W;
        float4* Wl = (float4*)Ws;
#pragma unroll
        for (int t = 0; t < 8; ++t) Wl[tid + t * 256] = Wg[tid + t * 256];
    }
    {
        int r = tid & 63, g = tid >> 6;
        int row = row0 + r;
        const float4* xr = (const float4*)(x + (size_t)row * 128);
#pragma unroll
        for (int t = 0; t < 8; ++t) {
            int k0 = g * 32 + t * 4;
            float4 v = (row < n) ? xr[k0 >> 2] : make_float4(0.f, 0.f, 0.f, 0.f);
            xsT[(k0 + 0) * 64 + r] = v.x;
            xsT[(k0 + 1) * 64 + r] = v.y;
            xsT[(k0 + 2) * 64 + r] = v.z;
            xsT[(k0 + 3) * 64 + r] = v.w;
        }
    }
    __syncthreads();
    const int tc = tid & 15;
    const int rg = tid >> 4;
    float acc[4][4];
#pragma unroll
    for (int i = 0; i < 4; ++i)
#pragma unroll
        for (int j = 0; j < 4; ++j) acc[i][j] = 0.f;
#pragma unroll 4
    for (int k = 0; k < 128; ++k) {
        float4 a = *(const float4*)&xsT[k * 64 + rg * 4];
        float4 b = *(const float4*)&Ws[k * 64 + tc * 4];
        acc[0][0] += a.x * b.x; acc[0][1] += a.x * b.y; acc[0][2] += a.x * b.z; acc[0][3] += a.x * b.w;
        acc[1][0] += a.y * b.x; acc[1][1] += a.y * b.y; acc[1][2] += a.y * b.z; acc[1][3] += a.y * b.w;
        acc[2][0] += a.z * b.x; acc[2][1] += a.z * b.y; acc[2][2] += a.z * b.z; acc[2][3] += a.z * b.w;
        acc[3][0] += a.w * b.x; acc[3][1] += a.w * b.y; acc[3][2] += a.w * b.z; acc[3][3] += a.w * b.w;
    }
#pragma unroll
    for (int i = 0; i < 4; ++i) {
        int row = row0 + rg * 4 + i;
        if (row < n)
            *(float4*)&h[(size_t)row * 64 + tc * 4] =
                make_float4(acc[i][0], acc[i][1], acc[i][2], acc[i][3]);
    }
}

__global__ __launch_bounds__(256) void k_gemm2_f(const float* __restrict__ agg,
                                                 const float* __restrict__ W2,
                                                 float* __restrict__ h2, int n) {
    __shared__ float Ws[64 * 40];
    __shared__ float hsT[64 * 64];
    const int tid = threadIdx.x;
    const int row0 = blockIdx.x * 64;
    {
        const float4* Wg = (const float4*)W2;
        float4* Wl = (float4*)Ws;
        for (int i = tid; i < 640; i += 256) Wl[i] = Wg[i];
    }
    {
        int r = tid & 63, g = tid >> 6;
        int row = row0 + r;
        const float4* ar = (const float4*)(agg + (size_t)row * 64);
#pragma unroll
        for (int t = 0; t < 4; ++t) {
            int k0 = g * 16 + t * 4;
            float4 v = (row < n) ? ar[k0 >> 2] : make_float4(0.f, 0.f, 0.f, 0.f);
            hsT[(k0 + 0) * 64 + r] = v.x > 0.f ? v.x : 0.f;
            hsT[(k0 + 1) * 64 + r] = v.y > 0.f ? v.y : 0.f;
            hsT[(k0 + 2) * 64 + r] = v.z > 0.f ? v.z : 0.f;
            hsT[(k0 + 3) * 64 + r] = v.w > 0.f ? v.w : 0.f;
        }
    }
    __syncthreads();
    const int tc = tid & 15;
    const int rg = tid >> 4;
    if (tc < 10) {
        float acc[4][4];
#pragma unroll
        for (int i = 0; i < 4; ++i)
#pragma unroll
            for (int j = 0; j < 4; ++j) acc[i][j] = 0.f;
#pragma unroll 4
        for (int k = 0; k < 64; ++k) {
            float4 a = *(const float4*)&hsT[k * 64 + rg * 4];
            float4 b = *(const float4*)&Ws[k * 40 + tc * 4];
            acc[0][0] += a.x * b.x; acc[0][1] += a.x * b.y; acc[0][2] += a.x * b.z; acc[0][3] += a.x * b.w;
            acc[1][0] += a.y * b.x; acc[1][1] += a.y * b.y; acc[1][2] += a.y * b.z; acc[1][3] += a.y * b.w;
            acc[2][0] += a.z * b.x; acc[2][1] += a.z * b.y; acc[2][2] += a.z * b.z; acc[2][3] += a.z * b.w;
            acc[3][0] += a.w * b.x; acc[3][1] += a.w * b.y; acc[3][2] += a.w * b.z; acc[3][3] += a.w * b.w;
        }
#pragma unroll
        for (int i = 0; i < 4; ++i) {
            int row = row0 + rg * 4 + i;
            if (row < n)
                *(float4*)&h2[(size_t)row * 40 + tc * 4] =
                    make_float4(acc[i][0], acc[i][1], acc[i][2], acc[i][3]);
        }
    }
}

__global__ void k_init_agg1(const float* __restrict__ h, const float* __restrict__ dinv,
                            const float* __restrict__ b1, float* __restrict__ agg, int n) {
    int idx = blockIdx.x * blockDim.x + threadIdx.x;
    if (idx < n * 64) {
        int i = idx >> 6, f = idx & 63;
        float d = dinv[i];
        agg[idx] = h[idx] * d * d + b1[f];
    }
}

__global__ __launch_bounds__(256) void k_scatter1(const float* __restrict__ h,
                                                  const int* __restrict__ src,
                                                  const int* __restrict__ dst,
                                                  const float* __restrict__ dinv,
                                                  float* __restrict__ agg, int E) {
    int e = blockIdx.x * 4 + (threadIdx.x >> 6);
    if (e >= E) return;
    int f = threadIdx.x & 63;
    int s = src[e], d = dst[e];
    float w = dinv[s] * dinv[d];
    atomicAdd(&agg[d * 64 + f], h[s * 64 + f] * w);
}

__global__ void k_init_out(const float* __restrict__ h2, const float* __restrict__ dinv,
                           const float* __restrict__ b2, float* __restrict__ out, int n) {
    int idx = blockIdx.x * blockDim.x + threadIdx.x;
    if (idx < n * 40) {
        int i = idx / 40;
        int f = idx - i * 40;
        float d = dinv[i];
        out[idx] = h2[idx] * d * d + b2[f];
    }
}

__global__ __launch_bounds__(256) void k_scatter2(const float* __restrict__ h2,
                                                  const int* __restrict__ src,
                                                  const int* __restrict__ dst,
                                                  const float* __restrict__ dinv,
                                                  float* __restrict__ out, int E) {
    int idx = blockIdx.x * blockDim.x + threadIdx.x;
    int total = E * 40;
    if (idx >= total) return;
    int e = idx / 40;
    int f = idx - e * 40;
    int s = src[e], d = dst[e];
    float w = dinv[s] * dinv[d];
    atomicAdd(&out[d * 40 + f], h2[s * 40 + f] * w);
}

extern "C" void kernel_launch(void* const* d_in, const int* in_sizes, int n_in,
                              void* d_out, int out_size, void* d_ws, size_t ws_size,
                              hipStream_t stream) {
    const float* x  = (const float*)d_in[0];
    const int*   ei = (const int*)d_in[1];
    const float* W1 = (const float*)d_in[2];
    const float* b1 = (const float*)d_in[3];
    const float* W2 = (const float*)d_in[4];
    const float* b2 = (const float*)d_in[5];
    float* out = (float*)d_out;

    const int n = in_sizes[0] / 128;   // 100000
    const int E = in_sizes[1] / 2;     // 1600000
    const int* src = ei;
    const int* dst = ei + E;

    char* ws = (char*)d_ws;
    const size_t MB = 1 << 20;
    float*  dinv   = (float*)(ws);                       // n floats
    int*    off    = (int*)  (ws + 512 * 1024);          // n+1 ints
    int*    bcnt   = (int*)  (ws + 1 * MB);              // NBCAP ints
    int*    bbase  = (int*)  (ws + 1 * MB + 8 * 1024);   // NBCAP+1 ints
    int*    bcur   = (int*)  (ws + 1 * MB + 16 * 1024);  // NBCAP ints
    __half* hs_h   = (__half*)(ws + 2 * MB);             // n*64 halves (12.8MB)
    __half* r2_h   = (__half*)(ws + 15 * MB);            // n*64 halves (12.8MB)
    __half* g2_h   = hs_h;                               // reuse (hs dead after gather1)
    int*    pairs  = (int*)  (ws + 28 * MB);             // E ints
    int*    csrc   = (int*)  (ws + 35 * MB);             // E ints
    size_t needed_fast = 35 * MB + (size_t)E * 4;

    const int nb = (n + NPB - 1) / NPB;

    if (ws_size >= needed_fast && nb <= NBCAP && n <= (1 << 17)) {
        // ---- CSC build via counting sort ----
        k_zero<<<(nb + 255) / 256, 256, 0, stream>>>(bcnt, nb);
        k_hist<<<512, 256, 0, stream>>>(dst, E, bcnt, nb);
        k_scan_nb<<<1, 1024, 0, stream>>>(bcnt, bbase, bcur, nb);
        k_binpass<<<(E + 4095) / 4096, 256, 0, stream>>>(src, dst, bcur, pairs, nb, E);
        k_bucket_build<<<nb, 256, 0, stream>>>(pairs, bbase, off, csrc, dinv, n, nb);

        const int GB = 2048;                 // persistent gather blocks
        const int NW = GB * 4;               // waves

        // ---- layer 1: hs = (x@W1)*dinv; r2 = relu(Ahat-agg + b1)*dinv ----
        k_gemm1_h<<<(n + 63) / 64, 256, 0, stream>>>(x, W1, hs_h, n, dinv);
        k_gather_h<<<GB, 256, 0, stream>>>(hs_h, off, csrc, dinv, b1, r2_h, n, NW, 0);

        // ---- layer 2: g2 = Ahat-agg(r2); out = g2 @ W2 + b2 ----
        k_gather_h<<<GB, 256, 0, stream>>>(r2_h, off, csrc, dinv, b1, g2_h, n, NW, 1);
        k_gemm2_out<<<(n + 63) / 64, 256, 0, stream>>>(g2_h, W2, b2, out, n);
    } else {
        // ---- fallback: fp32 atomic scatter path ----
        float* hlin = (float*)(ws + 2 * MB);
        float* agg1 = (float*)(ws + 28 * MB);
        k_init_deg<<<(n + 255) / 256, 256, 0, stream>>>(dinv, n);
        k_deg<<<(E + 255) / 256, 256, 0, stream>>>(dst, E, dinv);
        k_rsqrt<<<(n + 255) / 256, 256, 0, stream>>>(dinv, n);
        k_gemm1_f<<<(n + 63) / 64, 256, 0, stream>>>(x, W1, hlin, n);
        k_init_agg1<<<(n * 64 + 255) / 256, 256, 0, stream>>>(hlin, dinv, b1, agg1, n);
        k_scatter1<<<(E + 3) / 4, 256, 0, stream>>>(hlin, src, dst, dinv, agg1, E);
        k_gemm2_f<<<(n + 63) / 64, 256, 0, stream>>>(agg1, W2, hlin, n);
        k_init_out<<<(n * 40 + 255) / 256, 256, 0, stream>>>(hlin, dinv, b2, out, n);
        int total2 = E * 40;
        k_scatter2<<<(total2 + 255) / 256, 256, 0, stream>>>(hlin, src, dst, dinv, out, E);
    }
}

// Round 10
// 187.055 us; speedup vs baseline: 1.2041x; 1.0479x over previous
//
#include <hip/hip_runtime.h>
#include <hip/hip_fp16.h>

// ---------------------------------------------------------------------------
// GCN 2-layer forward: out = A_hat @ relu(A_hat @ (x@W1) + b1) @ W2 + b2
// A_hat = D^-1/2 (A + I) D^-1/2.
// Layer-2 algebra swap: out = (A_hat @ relu(agg1)) @ W2 + b2, so BOTH gathers
// run on 64-wide 128B-aligned fp16 rows (at the ~2.2TB/s random-access
// ceiling). gemm1 K-split into 2x64 halves: LDS 64->32KB, 2->5 blocks/CU.
// CSC via counting sort (round-7 proven, NPB=128).
// ---------------------------------------------------------------------------

#define NPB   128     // nodes per coarse bucket
#define NBCAP 1024    // max buckets supported by fast path

// ---------------- CSC build ----------------

__global__ void k_zero(int* __restrict__ p, int m) {
    int i = blockIdx.x * blockDim.x + threadIdx.x;
    if (i < m) p[i] = 0;
}

__global__ __launch_bounds__(256) void k_hist(const int* __restrict__ dst, int E,
                                              int* __restrict__ bcnt, int nb) {
    __shared__ int h[NBCAP];
    for (int i = threadIdx.x; i < nb; i += 256) h[i] = 0;
    __syncthreads();
    int stride = gridDim.x * 256;
    for (int e = blockIdx.x * 256 + threadIdx.x; e < E; e += stride)
        atomicAdd(&h[dst[e] >> 7], 1);
    __syncthreads();
    for (int i = threadIdx.x; i < nb; i += 256)
        if (h[i]) atomicAdd(&bcnt[i], h[i]);
}

__global__ __launch_bounds__(1024) void k_scan_nb(const int* __restrict__ bcnt,
                                                  int* __restrict__ bbase,
                                                  int* __restrict__ bcur, int nb) {
    __shared__ int tmp[NBCAP];
    int t = threadIdx.x;
    int v = (t < nb) ? bcnt[t] : 0;
    tmp[t] = v;
    __syncthreads();
    for (int ofs = 1; ofs < NBCAP; ofs <<= 1) {
        int u = (t >= ofs) ? tmp[t - ofs] : 0;
        __syncthreads();
        if (t >= ofs) tmp[t] += u;
        __syncthreads();
    }
    if (t < nb) {
        int ex = tmp[t] - v;
        bbase[t] = ex;
        bcur[t] = ex;
        if (t == nb - 1) bbase[nb] = tmp[t];
    }
}

__global__ __launch_bounds__(256) void k_binpass(const int* __restrict__ src,
                                                 const int* __restrict__ dst,
                                                 int* __restrict__ bcur,
                                                 int* __restrict__ pairs,
                                                 int nb, int E) {
    __shared__ int lh[NBCAP];
    __shared__ int lbase[NBCAP];
    for (int i = threadIdx.x; i < nb; i += 256) lh[i] = 0;
    __syncthreads();
    int base = blockIdx.x * 4096;
    int pk[16], bb[16];
#pragma unroll
    for (int k = 0; k < 16; ++k) {
        int e = base + k * 256 + threadIdx.x;
        if (e < E) {
            int d = dst[e];
            int b = d >> 7;
            bb[k] = b;
            pk[k] = src[e] | ((d & (NPB - 1)) << 17);
            atomicAdd(&lh[b], 1);
        } else bb[k] = -1;
    }
    __syncthreads();
    for (int i = threadIdx.x; i < nb; i += 256) {
        int c = lh[i];
        lbase[i] = c ? atomicAdd(&bcur[i], c) : 0;
        lh[i] = 0;
    }
    __syncthreads();
#pragma unroll
    for (int k = 0; k < 16; ++k) {
        if (bb[k] >= 0) {
            int r = atomicAdd(&lh[bb[k]], 1);
            pairs[lbase[bb[k]] + r] = pk[k];
        }
    }
}

__global__ __launch_bounds__(256) void k_bucket_build(const int* __restrict__ pairs,
                                                      const int* __restrict__ bbase,
                                                      int* __restrict__ off,
                                                      int* __restrict__ csrc,
                                                      float* __restrict__ dinv,
                                                      int n, int nb) {
    __shared__ int deg[NPB], sc[NPB], cur[NPB];
    int t = threadIdx.x;
    int bid = blockIdx.x;
    int node0 = bid * NPB;
    int ebeg = bbase[bid], eend = bbase[bid + 1];
    if (t < NPB) deg[t] = 0;
    __syncthreads();
    for (int e = ebeg + t; e < eend; e += 256)
        atomicAdd(&deg[pairs[e] >> 17], 1);
    __syncthreads();
    if (t < NPB) sc[t] = deg[t];
    __syncthreads();
    for (int ofs = 1; ofs < NPB; ofs <<= 1) {
        int u = (t < NPB && t >= ofs) ? sc[t - ofs] : 0;
        __syncthreads();
        if (t < NPB && t >= ofs) sc[t] += u;
        __syncthreads();
    }
    if (t < NPB) {
        int ex = sc[t] - deg[t];
        cur[t] = ex;
        int node = node0 + t;
        if (node < n) {
            off[node] = ebeg + ex;
            dinv[node] = rsqrtf((float)(deg[t] + 1));
        }
    }
    if (t == 0 && bid == nb - 1) off[n] = eend;
    __syncthreads();
    for (int e = ebeg + t; e < eend; e += 256) {
        int pkv = pairs[e];
        int r = atomicAdd(&cur[pkv >> 17], 1);
        csrc[ebeg + r] = pkv & 0x1FFFF;
    }
}

// ---------------- helpers ----------------

union pk2 { __half2 h[2]; uint2 u; };
union pk4 { __half2 h[4]; uint4 u; };

#define F4ADD(a, b) { (a).x += (b).x; (a).y += (b).y; (a).z += (b).z; (a).w += (b).w; }

__device__ __forceinline__ void acc8f(float4& lo, float4& hi, uint4 u) {
    __half2 h0 = *(__half2*)&u.x, h1 = *(__half2*)&u.y;
    __half2 h2v = *(__half2*)&u.z, h3v = *(__half2*)&u.w;
    float2 f0 = __half22float2(h0), f1 = __half22float2(h1);
    float2 f2 = __half22float2(h2v), f3 = __half22float2(h3v);
    lo.x += f0.x; lo.y += f0.y; lo.z += f1.x; lo.w += f1.y;
    hi.x += f2.x; hi.y += f2.y; hi.z += f3.x; hi.w += f3.y;
}

__device__ __forceinline__ void redstep(float4& lo, float4& hi, int delta, bool act) {
    float4 rl, rh;
    rl.x = __shfl_down(lo.x, delta); rl.y = __shfl_down(lo.y, delta);
    rl.z = __shfl_down(lo.z, delta); rl.w = __shfl_down(lo.w, delta);
    rh.x = __shfl_down(hi.x, delta); rh.y = __shfl_down(hi.y, delta);
    rh.z = __shfl_down(hi.z, delta); rh.w = __shfl_down(hi.w, delta);
    if (act) { F4ADD(lo, rl); F4ADD(hi, rh); }
}

// ---------------- dense layers ----------------

// hs[n,64] = (x[n,128] @ W1[128,64]) * dinv[row], fp16 out.
// K-split into 2 halves of 64: LDS = 16KB Ws + 16KB xsT = 32KB -> 5 blocks/CU.
__global__ __launch_bounds__(256) void k_gemm1_h(const float* __restrict__ x,
                                                 const float* __restrict__ W,
                                                 __half* __restrict__ h, int n,
                                                 const float* __restrict__ dinv) {
    __shared__ float Ws[64 * 64];     // [k][c] current K-half
    __shared__ float xsT[64 * 64];    // [k][r] current K-half
    const int tid = threadIdx.x;
    const int row0 = blockIdx.x * 64;
    const int tc = tid & 15;
    const int rg = tid >> 4;
    const int r = tid & 63, g = tid >> 6;
    const int row = row0 + r;

    float acc[4][4];
#pragma unroll
    for (int i = 0; i < 4; ++i)
#pragma unroll
        for (int j = 0; j < 4; ++j) acc[i][j] = 0.f;

#pragma unroll
    for (int kh = 0; kh < 2; ++kh) {
        // stage W half (64x64 floats = 1024 float4)
        {
            const float4* Wg = (const float4*)(W + kh * 64 * 64);
            float4* Wl = (float4*)Ws;
#pragma unroll
            for (int t = 0; t < 4; ++t) Wl[tid + t * 256] = Wg[tid + t * 256];
        }
        // stage x half transposed: row r, k in [kh*64, kh*64+64)
        {
            const float4* xr = (const float4*)(x + (size_t)row * 128 + kh * 64);
#pragma unroll
            for (int t = 0; t < 4; ++t) {
                int k0 = g * 16 + t * 4;
                float4 v = (row < n) ? xr[k0 >> 2] : make_float4(0.f, 0.f, 0.f, 0.f);
                xsT[(k0 + 0) * 64 + r] = v.x;
                xsT[(k0 + 1) * 64 + r] = v.y;
                xsT[(k0 + 2) * 64 + r] = v.z;
                xsT[(k0 + 3) * 64 + r] = v.w;
            }
        }
        __syncthreads();

#pragma unroll 4
        for (int k = 0; k < 64; ++k) {
            float4 a = *(const float4*)&xsT[k * 64 + rg * 4];
            float4 b = *(const float4*)&Ws[k * 64 + tc * 4];
            acc[0][0] += a.x * b.x; acc[0][1] += a.x * b.y; acc[0][2] += a.x * b.z; acc[0][3] += a.x * b.w;
            acc[1][0] += a.y * b.x; acc[1][1] += a.y * b.y; acc[1][2] += a.y * b.z; acc[1][3] += a.y * b.w;
            acc[2][0] += a.z * b.x; acc[2][1] += a.z * b.y; acc[2][2] += a.z * b.z; acc[2][3] += a.z * b.w;
            acc[3][0] += a.w * b.x; acc[3][1] += a.w * b.y; acc[3][2] += a.w * b.z; acc[3][3] += a.w * b.w;
        }
        __syncthreads();
    }

#pragma unroll
    for (int i = 0; i < 4; ++i) {
        int orow = row0 + rg * 4 + i;
        if (orow < n) {
            float dd = dinv[orow];
            pk2 p;
            p.h[0] = __floats2half2_rn(acc[i][0] * dd, acc[i][1] * dd);
            p.h[1] = __floats2half2_rn(acc[i][2] * dd, acc[i][3] * dd);
            *(uint2*)&h[(size_t)orow * 64 + tc * 4] = p.u;
        }
    }
}

// out[n,40] = g2[n,64] @ W2[64,40] + b2, fp32 out (g2 fp16, scales pre-applied).
__global__ __launch_bounds__(256) void k_gemm2_out(const __half* __restrict__ g2,
                                                   const float* __restrict__ W2,
                                                   const float* __restrict__ b2,
                                                   float* __restrict__ out, int n) {
    __shared__ float Ws[64 * 40];
    __shared__ float hsT[64 * 64];
    const int tid = threadIdx.x;
    const int row0 = blockIdx.x * 64;
    {
        const float4* Wg = (const float4*)W2;
        float4* Wl = (float4*)Ws;
        for (int i = tid; i < 640; i += 256) Wl[i] = Wg[i];
    }
    {
        int r = tid & 63, g = tid >> 6;
        int row = row0 + r;
        const __half* ar = g2 + (size_t)row * 64;
#pragma unroll
        for (int t = 0; t < 4; ++t) {
            int k0 = g * 16 + t * 4;
            float4 v = make_float4(0.f, 0.f, 0.f, 0.f);
            if (row < n) {
                uint2 u = *(const uint2*)(ar + k0);
                __half2 h0 = *(__half2*)&u.x, h1 = *(__half2*)&u.y;
                float2 f0 = __half22float2(h0), f1 = __half22float2(h1);
                v = make_float4(f0.x, f0.y, f1.x, f1.y);
            }
            hsT[(k0 + 0) * 64 + r] = v.x;
            hsT[(k0 + 1) * 64 + r] = v.y;
            hsT[(k0 + 2) * 64 + r] = v.z;
            hsT[(k0 + 3) * 64 + r] = v.w;
        }
    }
    __syncthreads();

    const int tc = tid & 15;
    const int rg = tid >> 4;
    if (tc < 10) {
        float acc[4][4];
#pragma unroll
        for (int i = 0; i < 4; ++i)
#pragma unroll
            for (int j = 0; j < 4; ++j) acc[i][j] = 0.f;

#pragma unroll 4
        for (int k = 0; k < 64; ++k) {
            float4 a = *(const float4*)&hsT[k * 64 + rg * 4];
            float4 b = *(const float4*)&Ws[k * 40 + tc * 4];
            acc[0][0] += a.x * b.x; acc[0][1] += a.x * b.y; acc[0][2] += a.x * b.z; acc[0][3] += a.x * b.w;
            acc[1][0] += a.y * b.x; acc[1][1] += a.y * b.y; acc[1][2] += a.y * b.z; acc[1][3] += a.y * b.w;
            acc[2][0] += a.z * b.x; acc[2][1] += a.z * b.y; acc[2][2] += a.z * b.z; acc[2][3] += a.z * b.w;
            acc[3][0] += a.w * b.x; acc[3][1] += a.w * b.y; acc[3][2] += a.w * b.z; acc[3][3] += a.w * b.w;
        }

        float4 bb = *(const float4*)(b2 + tc * 4);
#pragma unroll
        for (int i = 0; i < 4; ++i) {
            int row = row0 + rg * 4 + i;
            if (row < n)
                *(float4*)&out[(size_t)row * 40 + tc * 4] =
                    make_float4(acc[i][0] + bb.x, acc[i][1] + bb.y,
                                acc[i][2] + bb.z, acc[i][3] + bb.w);
        }
    }
}

// ---------------- gather: single-node waves, 64-wide fp16 rows ----------------

// mode 0 (layer1): o = relu((sum+self)*dd + bias) * dd   (emits r2)
// mode 1 (layer2): o = (sum+self)*dd                     (emits g2)
__global__ __launch_bounds__(256) void k_gather_h(const __half* __restrict__ feat,
                                                  const int* __restrict__ off,
                                                  const int* __restrict__ csrc,
                                                  const float* __restrict__ dinv,
                                                  const float* __restrict__ bias,
                                                  __half* __restrict__ outh,
                                                  int n, int nwaves, int mode) {
    int wid = (blockIdx.x * 256 + threadIdx.x) >> 6;
    int lane = threadIdx.x & 63;
    int g = lane >> 3, q = lane & 7;       // edge group / feature quad
    for (int node = wid; node < n; node += nwaves) {
        int beg = off[node], end = off[node + 1];
        float4 a0 = make_float4(0.f, 0.f, 0.f, 0.f);
        float4 a1 = make_float4(0.f, 0.f, 0.f, 0.f);
        float4 c0 = make_float4(0.f, 0.f, 0.f, 0.f);
        float4 c1 = make_float4(0.f, 0.f, 0.f, 0.f);
        int j = beg;
        for (; j + 16 <= end; j += 16) {
            int s0 = csrc[j + g];
            int s1 = csrc[j + 8 + g];
            uint4 u0 = *(const uint4*)(feat + ((size_t)s0 << 6) + (q << 3));
            uint4 u1 = *(const uint4*)(feat + ((size_t)s1 << 6) + (q << 3));
            acc8f(a0, a1, u0);
            acc8f(c0, c1, u1);
        }
        for (; j + 8 <= end; j += 8) {
            int s0 = csrc[j + g];
            uint4 u0 = *(const uint4*)(feat + ((size_t)s0 << 6) + (q << 3));
            acc8f(a0, a1, u0);
        }
        if (j + g < end) {
            int s0 = csrc[j + g];
            uint4 u0 = *(const uint4*)(feat + ((size_t)s0 << 6) + (q << 3));
            acc8f(a0, a1, u0);
        }
        F4ADD(a0, c0); F4ADD(a1, c1);
        redstep(a0, a1, 32, lane < 32);
        redstep(a0, a1, 16, lane < 16);
        redstep(a0, a1, 8,  lane < 8);
        if (lane < 8) {
            float dd = dinv[node];
            uint4 us = *(const uint4*)(feat + ((size_t)node << 6) + (q << 3));
            float4 slo = make_float4(0.f, 0.f, 0.f, 0.f);
            float4 shi = make_float4(0.f, 0.f, 0.f, 0.f);
            acc8f(slo, shi, us);
            float f0 = (a0.x + slo.x) * dd;
            float f1 = (a0.y + slo.y) * dd;
            float f2 = (a0.z + slo.z) * dd;
            float f3 = (a0.w + slo.w) * dd;
            float f4 = (a1.x + shi.x) * dd;
            float f5 = (a1.y + shi.y) * dd;
            float f6 = (a1.z + shi.z) * dd;
            float f7 = (a1.w + shi.w) * dd;
            if (mode == 0) {
                float4 blo = *(const float4*)(bias + q * 8);
                float4 bhi = *(const float4*)(bias + q * 8 + 4);
                f0 += blo.x; f1 += blo.y; f2 += blo.z; f3 += blo.w;
                f4 += bhi.x; f5 += bhi.y; f6 += bhi.z; f7 += bhi.w;
                f0 = (f0 > 0.f ? f0 : 0.f) * dd;
                f1 = (f1 > 0.f ? f1 : 0.f) * dd;
                f2 = (f2 > 0.f ? f2 : 0.f) * dd;
                f3 = (f3 > 0.f ? f3 : 0.f) * dd;
                f4 = (f4 > 0.f ? f4 : 0.f) * dd;
                f5 = (f5 > 0.f ? f5 : 0.f) * dd;
                f6 = (f6 > 0.f ? f6 : 0.f) * dd;
                f7 = (f7 > 0.f ? f7 : 0.f) * dd;
            }
            pk4 p;
            p.h[0] = __floats2half2_rn(f0, f1);
            p.h[1] = __floats2half2_rn(f2, f3);
            p.h[2] = __floats2half2_rn(f4, f5);
            p.h[3] = __floats2half2_rn(f6, f7);
            *(uint4*)&outh[((size_t)node << 6) + (q << 3)] = p.u;
        }
    }
}

// ---------------- fallback atomic-scatter path (fp32, proven) ----------------

__global__ void k_init_deg(float* __restrict__ deg, int n) {
    int i = blockIdx.x * blockDim.x + threadIdx.x;
    if (i < n) deg[i] = 1.0f;
}

__global__ void k_deg(const int* __restrict__ dst, int E, float* __restrict__ deg) {
    int i = blockIdx.x * blockDim.x + threadIdx.x;
    if (i < E) atomicAdd(&deg[dst[i]], 1.0f);
}

__global__ void k_rsqrt(float* __restrict__ deg, int n) {
    int i = blockIdx.x * blockDim.x + threadIdx.x;
    if (i < n) deg[i] = rsqrtf(deg[i]);
}

__global__ __launch_bounds__(256) void k_gemm1_f(const float* __restrict__ x,
                                                 const float* __restrict__ W,
                                                 float* __restrict__ h, int n) {
    __shared__ float Ws[128 * 64];
    __shared__ float xsT[128 * 64];
    const int tid = threadIdx.x;
    const int row0 = blockIdx.x * 64;
    {
        const float4* Wg = (const float4*)W;
        float4* Wl = (float4*)Ws;
#pragma unroll
        for (int t = 0; t < 8; ++t) Wl[tid + t * 256] = Wg[tid + t * 256];
    }
    {
        int r = tid & 63, g = tid >> 6;
        int row = row0 + r;
        const float4* xr = (const float4*)(x + (size_t)row * 128);
#pragma unroll
        for (int t = 0; t < 8; ++t) {
            int k0 = g * 32 + t * 4;
            float4 v = (row < n) ? xr[k0 >> 2] : make_float4(0.f, 0.f, 0.f, 0.f);
            xsT[(k0 + 0) * 64 + r] = v.x;
            xsT[(k0 + 1) * 64 + r] = v.y;
            xsT[(k0 + 2) * 64 + r] = v.z;
            xsT[(k0 + 3) * 64 + r] = v.w;
        }
    }
    __syncthreads();
    const int tc = tid & 15;
    const int rg = tid >> 4;
    float acc[4][4];
#pragma unroll
    for (int i = 0; i < 4; ++i)
#pragma unroll
        for (int j = 0; j < 4; ++j) acc[i][j] = 0.f;
#pragma unroll 4
    for (int k = 0; k < 128; ++k) {
        float4 a = *(const float4*)&xsT[k * 64 + rg * 4];
        float4 b = *(const float4*)&Ws[k * 64 + tc * 4];
        acc[0][0] += a.x * b.x; acc[0][1] += a.x * b.y; acc[0][2] += a.x * b.z; acc[0][3] += a.x * b.w;
        acc[1][0] += a.y * b.x; acc[1][1] += a.y * b.y; acc[1][2] += a.y * b.z; acc[1][3] += a.y * b.w;
        acc[2][0] += a.z * b.x; acc[2][1] += a.z * b.y; acc[2][2] += a.z * b.z; acc[2][3] += a.z * b.w;
        acc[3][0] += a.w * b.x; acc[3][1] += a.w * b.y; acc[3][2] += a.w * b.z; acc[3][3] += a.w * b.w;
    }
#pragma unroll
    for (int i = 0; i < 4; ++i) {
        int row = row0 + rg * 4 + i;
        if (row < n)
            *(float4*)&h[(size_t)row * 64 + tc * 4] =
                make_float4(acc[i][0], acc[i][1], acc[i][2], acc[i][3]);
    }
}

__global__ __launch_bounds__(256) void k_gemm2_f(const float* __restrict__ agg,
                                                 const float* __restrict__ W2,
                                                 float* __restrict__ h2, int n) {
    __shared__ float Ws[64 * 40];
    __shared__ float hsT[64 * 64];
    const int tid = threadIdx.x;
    const int row0 = blockIdx.x * 64;
    {
        const float4* Wg = (const float4*)W2;
        float4* Wl = (float4*)Ws;
        for (int i = tid; i < 640; i += 256) Wl[i] = Wg[i];
    }
    {
        int r = tid & 63, g = tid >> 6;
        int row = row0 + r;
        const float4* ar = (const float4*)(agg + (size_t)row * 64);
#pragma unroll
        for (int t = 0; t < 4; ++t) {
            int k0 = g * 16 + t * 4;
            float4 v = (row < n) ? ar[k0 >> 2] : make_float4(0.f, 0.f, 0.f, 0.f);
            hsT[(k0 + 0) * 64 + r] = v.x > 0.f ? v.x : 0.f;
            hsT[(k0 + 1) * 64 + r] = v.y > 0.f ? v.y : 0.f;
            hsT[(k0 + 2) * 64 + r] = v.z > 0.f ? v.z : 0.f;
            hsT[(k0 + 3) * 64 + r] = v.w > 0.f ? v.w : 0.f;
        }
    }
    __syncthreads();
    const int tc = tid & 15;
    const int rg = tid >> 4;
    if (tc < 10) {
        float acc[4][4];
#pragma unroll
        for (int i = 0; i < 4; ++i)
#pragma unroll
            for (int j = 0; j < 4; ++j) acc[i][j] = 0.f;
#pragma unroll 4
        for (int k = 0; k < 64; ++k) {
            float4 a = *(const float4*)&hsT[k * 64 + rg * 4];
            float4 b = *(const float4*)&Ws[k * 40 + tc * 4];
            acc[0][0] += a.x * b.x; acc[0][1] += a.x * b.y; acc[0][2] += a.x * b.z; acc[0][3] += a.x * b.w;
            acc[1][0] += a.y * b.x; acc[1][1] += a.y * b.y; acc[1][2] += a.y * b.z; acc[1][3] += a.y * b.w;
            acc[2][0] += a.z * b.x; acc[2][1] += a.z * b.y; acc[2][2] += a.z * b.z; acc[2][3] += a.z * b.w;
            acc[3][0] += a.w * b.x; acc[3][1] += a.w * b.y; acc[3][2] += a.w * b.z; acc[3][3] += a.w * b.w;
        }
#pragma unroll
        for (int i = 0; i < 4; ++i) {
            int row = row0 + rg * 4 + i;
            if (row < n)
                *(float4*)&h2[(size_t)row * 40 + tc * 4] =
                    make_float4(acc[i][0], acc[i][1], acc[i][2], acc[i][3]);
        }
    }
}

__global__ void k_init_agg1(const float* __restrict__ h, const float* __restrict__ dinv,
                            const float* __restrict__ b1, float* __restrict__ agg, int n) {
    int idx = blockIdx.x * blockDim.x + threadIdx.x;
    if (idx < n * 64) {
        int i = idx >> 6, f = idx & 63;
        float d = dinv[i];
        agg[idx] = h[idx] * d * d + b1[f];
    }
}

__global__ __launch_bounds__(256) void k_scatter1(const float* __restrict__ h,
                                                  const int* __restrict__ src,
                                                  const int* __restrict__ dst,
                                                  const float* __restrict__ dinv,
                                                  float* __restrict__ agg, int E) {
    int e = blockIdx.x * 4 + (threadIdx.x >> 6);
    if (e >= E) return;
    int f = threadIdx.x & 63;
    int s = src[e], d = dst[e];
    float w = dinv[s] * dinv[d];
    atomicAdd(&agg[d * 64 + f], h[s * 64 + f] * w);
}

__global__ void k_init_out(const float* __restrict__ h2, const float* __restrict__ dinv,
                           const float* __restrict__ b2, float* __restrict__ out, int n) {
    int idx = blockIdx.x * blockDim.x + threadIdx.x;
    if (idx < n * 40) {
        int i = idx / 40;
        int f = idx - i * 40;
        float d = dinv[i];
        out[idx] = h2[idx] * d * d + b2[f];
    }
}

__global__ __launch_bounds__(256) void k_scatter2(const float* __restrict__ h2,
                                                  const int* __restrict__ src,
                                                  const int* __restrict__ dst,
                                                  const float* __restrict__ dinv,
                                                  float* __restrict__ out, int E) {
    int idx = blockIdx.x * blockDim.x + threadIdx.x;
    int total = E * 40;
    if (idx >= total) return;
    int e = idx / 40;
    int f = idx - e * 40;
    int s = src[e], d = dst[e];
    float w = dinv[s] * dinv[d];
    atomicAdd(&out[d * 40 + f], h2[s * 40 + f] * w);
}

extern "C" void kernel_launch(void* const* d_in, const int* in_sizes, int n_in,
                              void* d_out, int out_size, void* d_ws, size_t ws_size,
                              hipStream_t stream) {
    const float* x  = (const float*)d_in[0];
    const int*   ei = (const int*)d_in[1];
    const float* W1 = (const float*)d_in[2];
    const float* b1 = (const float*)d_in[3];
    const float* W2 = (const float*)d_in[4];
    const float* b2 = (const float*)d_in[5];
    float* out = (float*)d_out;

    const int n = in_sizes[0] / 128;   // 100000
    const int E = in_sizes[1] / 2;     // 1600000
    const int* src = ei;
    const int* dst = ei + E;

    char* ws = (char*)d_ws;
    const size_t MB = 1 << 20;
    float*  dinv   = (float*)(ws);                       // n floats
    int*    off    = (int*)  (ws + 512 * 1024);          // n+1 ints
    int*    bcnt   = (int*)  (ws + 1 * MB);              // NBCAP ints
    int*    bbase  = (int*)  (ws + 1 * MB + 8 * 1024);   // NBCAP+1 ints
    int*    bcur   = (int*)  (ws + 1 * MB + 16 * 1024);  // NBCAP ints
    __half* hs_h   = (__half*)(ws + 2 * MB);             // n*64 halves (12.8MB)
    __half* r2_h   = (__half*)(ws + 15 * MB);            // n*64 halves (12.8MB)
    __half* g2_h   = hs_h;                               // reuse (hs dead after gather1)
    int*    pairs  = (int*)  (ws + 28 * MB);             // E ints
    int*    csrc   = (int*)  (ws + 35 * MB);             // E ints
    size_t needed_fast = 35 * MB + (size_t)E * 4;

    const int nb = (n + NPB - 1) / NPB;

    if (ws_size >= needed_fast && nb <= NBCAP && n <= (1 << 17)) {
        // ---- CSC build via counting sort ----
        k_zero<<<(nb + 255) / 256, 256, 0, stream>>>(bcnt, nb);
        k_hist<<<512, 256, 0, stream>>>(dst, E, bcnt, nb);
        k_scan_nb<<<1, 1024, 0, stream>>>(bcnt, bbase, bcur, nb);
        k_binpass<<<(E + 4095) / 4096, 256, 0, stream>>>(src, dst, bcur, pairs, nb, E);
        k_bucket_build<<<nb, 256, 0, stream>>>(pairs, bbase, off, csrc, dinv, n, nb);

        const int GB = 2048;                 // persistent gather blocks
        const int NW = GB * 4;               // waves

        // ---- layer 1: hs = (x@W1)*dinv; r2 = relu(Ahat-agg + b1)*dinv ----
        k_gemm1_h<<<(n + 63) / 64, 256, 0, stream>>>(x, W1, hs_h, n, dinv);
        k_gather_h<<<GB, 256, 0, stream>>>(hs_h, off, csrc, dinv, b1, r2_h, n, NW, 0);

        // ---- layer 2: g2 = Ahat-agg(r2); out = g2 @ W2 + b2 ----
        k_gather_h<<<GB, 256, 0, stream>>>(r2_h, off, csrc, dinv, b1, g2_h, n, NW, 1);
        k_gemm2_out<<<(n + 63) / 64, 256, 0, stream>>>(g2_h, W2, b2, out, n);
    } else {
        // ---- fallback: fp32 atomic scatter path ----
        float* hlin = (float*)(ws + 2 * MB);
        float* agg1 = (float*)(ws + 28 * MB);
        k_init_deg<<<(n + 255) / 256, 256, 0, stream>>>(dinv, n);
        k_deg<<<(E + 255) / 256, 256, 0, stream>>>(dst, E, dinv);
        k_rsqrt<<<(n + 255) / 256, 256, 0, stream>>>(dinv, n);
        k_gemm1_f<<<(n + 63) / 64, 256, 0, stream>>>(x, W1, hlin, n);
        k_init_agg1<<<(n * 64 + 255) / 256, 256, 0, stream>>>(hlin, dinv, b1, agg1, n);
        k_scatter1<<<(E + 3) / 4, 256, 0, stream>>>(hlin, src, dst, dinv, agg1, E);
        k_gemm2_f<<<(n + 63) / 64, 256, 0, stream>>>(agg1, W2, hlin, n);
        k_init_out<<<(n * 40 + 255) / 256, 256, 0, stream>>>(hlin, dinv, b2, out, n);
        int total2 = E * 40;
        k_scatter2<<<(total2 + 255) / 256, 256, 0, stream>>>(hlin, src, dst, dinv, out, E);
    }
}

// Round 11
// 186.447 us; speedup vs baseline: 1.2080x; 1.0033x over previous
//
#include <hip/hip_runtime.h>
#include <hip/hip_fp16.h>

// ---------------------------------------------------------------------------
// GCN 2-layer forward: out = A_hat @ relu(A_hat @ (x@W1) + b1) @ W2 + b2
// A_hat = D^-1/2 (A + I) D^-1/2.
// Layer-2 algebra swap: out = (A_hat @ relu(agg1)) @ W2 + b2, so BOTH gathers
// run on 64-wide 128B-aligned fp16 rows (at the ~2.2TB/s random-access
// ceiling). gemm1 K-split 2x64 (32KB LDS). CSC counting sort with NPB=256
// (halves binpass partial-line write waste). Gather inner loop pre-adds edge
// pairs in fp16 (v_pk_add_f16) to cut cvt VALU 25%.
// ---------------------------------------------------------------------------

#define NPB      256     // nodes per bucket
#define NB_SHIFT 8
#define NBCAP    512     // max buckets (n <= 131072)

// ---------------- CSC build ----------------

__global__ void k_zero(int* __restrict__ p, int m) {
    int i = blockIdx.x * blockDim.x + threadIdx.x;
    if (i < m) p[i] = 0;
}

__global__ __launch_bounds__(256) void k_hist(const int* __restrict__ dst, int E,
                                              int* __restrict__ bcnt, int nb) {
    __shared__ int h[NBCAP];
    for (int i = threadIdx.x; i < nb; i += 256) h[i] = 0;
    __syncthreads();
    int stride = gridDim.x * 256;
    for (int e = blockIdx.x * 256 + threadIdx.x; e < E; e += stride)
        atomicAdd(&h[dst[e] >> NB_SHIFT], 1);
    __syncthreads();
    for (int i = threadIdx.x; i < nb; i += 256)
        if (h[i]) atomicAdd(&bcnt[i], h[i]);
}

__global__ __launch_bounds__(512) void k_scan_nb(const int* __restrict__ bcnt,
                                                 int* __restrict__ bbase,
                                                 int* __restrict__ bcur, int nb) {
    __shared__ int tmp[512];
    int t = threadIdx.x;
    int v = (t < nb) ? bcnt[t] : 0;
    tmp[t] = v;
    __syncthreads();
    for (int ofs = 1; ofs < 512; ofs <<= 1) {
        int u = (t >= ofs) ? tmp[t - ofs] : 0;
        __syncthreads();
        if (t >= ofs) tmp[t] += u;
        __syncthreads();
    }
    if (t < nb) {
        int ex = tmp[t] - v;
        bbase[t] = ex;
        bcur[t] = ex;
        if (t == nb - 1) bbase[nb] = tmp[t];
    }
}

// Partition edges into buckets as packed (src | ldst<<17), ldst < 256.
__global__ __launch_bounds__(256) void k_binpass(const int* __restrict__ src,
                                                 const int* __restrict__ dst,
                                                 int* __restrict__ bcur,
                                                 int* __restrict__ pairs,
                                                 int nb, int E) {
    __shared__ int lh[NBCAP];
    __shared__ int lbase[NBCAP];
    for (int i = threadIdx.x; i < nb; i += 256) lh[i] = 0;
    __syncthreads();
    int base = blockIdx.x * 4096;
    int pk[16], bb[16];
#pragma unroll
    for (int k = 0; k < 16; ++k) {
        int e = base + k * 256 + threadIdx.x;
        if (e < E) {
            int d = dst[e];
            int b = d >> NB_SHIFT;
            bb[k] = b;
            pk[k] = src[e] | ((d & (NPB - 1)) << 17);
            atomicAdd(&lh[b], 1);
        } else bb[k] = -1;
    }
    __syncthreads();
    for (int i = threadIdx.x; i < nb; i += 256) {
        int c = lh[i];
        lbase[i] = c ? atomicAdd(&bcur[i], c) : 0;
        lh[i] = 0;
    }
    __syncthreads();
#pragma unroll
    for (int k = 0; k < 16; ++k) {
        if (bb[k] >= 0) {
            int r = atomicAdd(&lh[bb[k]], 1);
            pairs[lbase[bb[k]] + r] = pk[k];
        }
    }
}

// One block per bucket (256 nodes): LDS deg count + scan -> off/dinv; fill csrc.
__global__ __launch_bounds__(256) void k_bucket_build(const int* __restrict__ pairs,
                                                      const int* __restrict__ bbase,
                                                      int* __restrict__ off,
                                                      int* __restrict__ csrc,
                                                      float* __restrict__ dinv,
                                                      int n, int nb) {
    __shared__ int deg[NPB], sc[NPB], cur[NPB];
    int t = threadIdx.x;
    int bid = blockIdx.x;
    int node0 = bid * NPB;
    int ebeg = bbase[bid], eend = bbase[bid + 1];
    deg[t] = 0;
    __syncthreads();
    for (int e = ebeg + t; e < eend; e += 256)
        atomicAdd(&deg[pairs[e] >> 17], 1);
    __syncthreads();
    sc[t] = deg[t];
    __syncthreads();
    for (int ofs = 1; ofs < NPB; ofs <<= 1) {
        int u = (t >= ofs) ? sc[t - ofs] : 0;
        __syncthreads();
        if (t >= ofs) sc[t] += u;
        __syncthreads();
    }
    {
        int ex = sc[t] - deg[t];
        cur[t] = ex;
        int node = node0 + t;
        if (node < n) {
            off[node] = ebeg + ex;
            dinv[node] = rsqrtf((float)(deg[t] + 1));
        }
    }
    if (t == 0 && bid == nb - 1) off[n] = eend;
    __syncthreads();
    for (int e = ebeg + t; e < eend; e += 256) {
        int pkv = pairs[e];
        int r = atomicAdd(&cur[pkv >> 17], 1);
        csrc[ebeg + r] = pkv & 0x1FFFF;
    }
}

// ---------------- helpers ----------------

union pk2 { __half2 h[2]; uint2 u; };
union pk4 { __half2 h[4]; uint4 u; };

#define F4ADD(a, b) { (a).x += (b).x; (a).y += (b).y; (a).z += (b).z; (a).w += (b).w; }

__device__ __forceinline__ void acc8f(float4& lo, float4& hi, uint4 u) {
    __half2 h0 = *(__half2*)&u.x, h1 = *(__half2*)&u.y;
    __half2 h2v = *(__half2*)&u.z, h3v = *(__half2*)&u.w;
    float2 f0 = __half22float2(h0), f1 = __half22float2(h1);
    float2 f2 = __half22float2(h2v), f3 = __half22float2(h3v);
    lo.x += f0.x; lo.y += f0.y; lo.z += f1.x; lo.w += f1.y;
    hi.x += f2.x; hi.y += f2.y; hi.z += f3.x; hi.w += f3.y;
}

// fp16 pairwise add of two uint4 rows (4 v_pk_add_f16)
__device__ __forceinline__ uint4 hpadd(uint4 a, uint4 b) {
    pk4 pa, pb, pr;
    pa.u = a; pb.u = b;
    pr.h[0] = __hadd2(pa.h[0], pb.h[0]);
    pr.h[1] = __hadd2(pa.h[1], pb.h[1]);
    pr.h[2] = __hadd2(pa.h[2], pb.h[2]);
    pr.h[3] = __hadd2(pa.h[3], pb.h[3]);
    return pr.u;
}

__device__ __forceinline__ void redstep(float4& lo, float4& hi, int delta, bool act) {
    float4 rl, rh;
    rl.x = __shfl_down(lo.x, delta); rl.y = __shfl_down(lo.y, delta);
    rl.z = __shfl_down(lo.z, delta); rl.w = __shfl_down(lo.w, delta);
    rh.x = __shfl_down(hi.x, delta); rh.y = __shfl_down(hi.y, delta);
    rh.z = __shfl_down(hi.z, delta); rh.w = __shfl_down(hi.w, delta);
    if (act) { F4ADD(lo, rl); F4ADD(hi, rh); }
}

// ---------------- dense layers ----------------

// hs[n,64] = (x[n,128] @ W1[128,64]) * dinv[row], fp16 out. K-split 2x64.
__global__ __launch_bounds__(256) void k_gemm1_h(const float* __restrict__ x,
                                                 const float* __restrict__ W,
                                                 __half* __restrict__ h, int n,
                                                 const float* __restrict__ dinv) {
    __shared__ float Ws[64 * 64];
    __shared__ float xsT[64 * 64];
    const int tid = threadIdx.x;
    const int row0 = blockIdx.x * 64;
    const int tc = tid & 15;
    const int rg = tid >> 4;
    const int r = tid & 63, g = tid >> 6;
    const int row = row0 + r;

    float acc[4][4];
#pragma unroll
    for (int i = 0; i < 4; ++i)
#pragma unroll
        for (int j = 0; j < 4; ++j) acc[i][j] = 0.f;

#pragma unroll
    for (int kh = 0; kh < 2; ++kh) {
        {
            const float4* Wg = (const float4*)(W + kh * 64 * 64);
            float4* Wl = (float4*)Ws;
#pragma unroll
            for (int t = 0; t < 4; ++t) Wl[tid + t * 256] = Wg[tid + t * 256];
        }
        {
            const float4* xr = (const float4*)(x + (size_t)row * 128 + kh * 64);
#pragma unroll
            for (int t = 0; t < 4; ++t) {
                int k0 = g * 16 + t * 4;
                float4 v = (row < n) ? xr[k0 >> 2] : make_float4(0.f, 0.f, 0.f, 0.f);
                xsT[(k0 + 0) * 64 + r] = v.x;
                xsT[(k0 + 1) * 64 + r] = v.y;
                xsT[(k0 + 2) * 64 + r] = v.z;
                xsT[(k0 + 3) * 64 + r] = v.w;
            }
        }
        __syncthreads();

#pragma unroll 4
        for (int k = 0; k < 64; ++k) {
            float4 a = *(const float4*)&xsT[k * 64 + rg * 4];
            float4 b = *(const float4*)&Ws[k * 64 + tc * 4];
            acc[0][0] += a.x * b.x; acc[0][1] += a.x * b.y; acc[0][2] += a.x * b.z; acc[0][3] += a.x * b.w;
            acc[1][0] += a.y * b.x; acc[1][1] += a.y * b.y; acc[1][2] += a.y * b.z; acc[1][3] += a.y * b.w;
            acc[2][0] += a.z * b.x; acc[2][1] += a.z * b.y; acc[2][2] += a.z * b.z; acc[2][3] += a.z * b.w;
            acc[3][0] += a.w * b.x; acc[3][1] += a.w * b.y; acc[3][2] += a.w * b.z; acc[3][3] += a.w * b.w;
        }
        __syncthreads();
    }

#pragma unroll
    for (int i = 0; i < 4; ++i) {
        int orow = row0 + rg * 4 + i;
        if (orow < n) {
            float dd = dinv[orow];
            pk2 p;
            p.h[0] = __floats2half2_rn(acc[i][0] * dd, acc[i][1] * dd);
            p.h[1] = __floats2half2_rn(acc[i][2] * dd, acc[i][3] * dd);
            *(uint2*)&h[(size_t)orow * 64 + tc * 4] = p.u;
        }
    }
}

// out[n,40] = g2[n,64] @ W2[64,40] + b2, fp32 out (g2 fp16, scales pre-applied).
__global__ __launch_bounds__(256) void k_gemm2_out(const __half* __restrict__ g2,
                                                   const float* __restrict__ W2,
                                                   const float* __restrict__ b2,
                                                   float* __restrict__ out, int n) {
    __shared__ float Ws[64 * 40];
    __shared__ float hsT[64 * 64];
    const int tid = threadIdx.x;
    const int row0 = blockIdx.x * 64;
    {
        const float4* Wg = (const float4*)W2;
        float4* Wl = (float4*)Ws;
        for (int i = tid; i < 640; i += 256) Wl[i] = Wg[i];
    }
    {
        int r = tid & 63, g = tid >> 6;
        int row = row0 + r;
        const __half* ar = g2 + (size_t)row * 64;
#pragma unroll
        for (int t = 0; t < 4; ++t) {
            int k0 = g * 16 + t * 4;
            float4 v = make_float4(0.f, 0.f, 0.f, 0.f);
            if (row < n) {
                uint2 u = *(const uint2*)(ar + k0);
                __half2 h0 = *(__half2*)&u.x, h1 = *(__half2*)&u.y;
                float2 f0 = __half22float2(h0), f1 = __half22float2(h1);
                v = make_float4(f0.x, f0.y, f1.x, f1.y);
            }
            hsT[(k0 + 0) * 64 + r] = v.x;
            hsT[(k0 + 1) * 64 + r] = v.y;
            hsT[(k0 + 2) * 64 + r] = v.z;
            hsT[(k0 + 3) * 64 + r] = v.w;
        }
    }
    __syncthreads();

    const int tc = tid & 15;
    const int rg = tid >> 4;
    if (tc < 10) {
        float acc[4][4];
#pragma unroll
        for (int i = 0; i < 4; ++i)
#pragma unroll
            for (int j = 0; j < 4; ++j) acc[i][j] = 0.f;

#pragma unroll 4
        for (int k = 0; k < 64; ++k) {
            float4 a = *(const float4*)&hsT[k * 64 + rg * 4];
            float4 b = *(const float4*)&Ws[k * 40 + tc * 4];
            acc[0][0] += a.x * b.x; acc[0][1] += a.x * b.y; acc[0][2] += a.x * b.z; acc[0][3] += a.x * b.w;
            acc[1][0] += a.y * b.x; acc[1][1] += a.y * b.y; acc[1][2] += a.y * b.z; acc[1][3] += a.y * b.w;
            acc[2][0] += a.z * b.x; acc[2][1] += a.z * b.y; acc[2][2] += a.z * b.z; acc[2][3] += a.z * b.w;
            acc[3][0] += a.w * b.x; acc[3][1] += a.w * b.y; acc[3][2] += a.w * b.z; acc[3][3] += a.w * b.w;
        }

        float4 bb = *(const float4*)(b2 + tc * 4);
#pragma unroll
        for (int i = 0; i < 4; ++i) {
            int row = row0 + rg * 4 + i;
            if (row < n)
                *(float4*)&out[(size_t)row * 40 + tc * 4] =
                    make_float4(acc[i][0] + bb.x, acc[i][1] + bb.y,
                                acc[i][2] + bb.z, acc[i][3] + bb.w);
        }
    }
}

// ---------------- gather: single-node waves, 64-wide fp16 rows ----------------

// mode 0 (layer1): o = relu((sum+self)*dd + bias) * dd   (emits r2)
// mode 1 (layer2): o = (sum+self)*dd                     (emits g2)
__global__ __launch_bounds__(256) void k_gather_h(const __half* __restrict__ feat,
                                                  const int* __restrict__ off,
                                                  const int* __restrict__ csrc,
                                                  const float* __restrict__ dinv,
                                                  const float* __restrict__ bias,
                                                  __half* __restrict__ outh,
                                                  int n, int nwaves, int mode) {
    int wid = (blockIdx.x * 256 + threadIdx.x) >> 6;
    int lane = threadIdx.x & 63;
    int g = lane >> 3, q = lane & 7;       // edge group / feature quad
    for (int node = wid; node < n; node += nwaves) {
        int beg = off[node], end = off[node + 1];
        float4 a0 = make_float4(0.f, 0.f, 0.f, 0.f);
        float4 a1 = make_float4(0.f, 0.f, 0.f, 0.f);
        int j = beg;
        for (; j + 16 <= end; j += 16) {
            int s0 = csrc[j + g];
            int s1 = csrc[j + 8 + g];
            uint4 u0 = *(const uint4*)(feat + ((size_t)s0 << 6) + (q << 3));
            uint4 u1 = *(const uint4*)(feat + ((size_t)s1 << 6) + (q << 3));
            acc8f(a0, a1, hpadd(u0, u1));   // fp16 pair pre-add, fp32 accumulate
        }
        for (; j + 8 <= end; j += 8) {
            int s0 = csrc[j + g];
            uint4 u0 = *(const uint4*)(feat + ((size_t)s0 << 6) + (q << 3));
            acc8f(a0, a1, u0);
        }
        if (j + g < end) {
            int s0 = csrc[j + g];
            uint4 u0 = *(const uint4*)(feat + ((size_t)s0 << 6) + (q << 3));
            acc8f(a0, a1, u0);
        }
        redstep(a0, a1, 32, lane < 32);
        redstep(a0, a1, 16, lane < 16);
        redstep(a0, a1, 8,  lane < 8);
        if (lane < 8) {
            float dd = dinv[node];
            uint4 us = *(const uint4*)(feat + ((size_t)node << 6) + (q << 3));
            float4 slo = make_float4(0.f, 0.f, 0.f, 0.f);
            float4 shi = make_float4(0.f, 0.f, 0.f, 0.f);
            acc8f(slo, shi, us);
            float f0 = (a0.x + slo.x) * dd;
            float f1 = (a0.y + slo.y) * dd;
            float f2 = (a0.z + slo.z) * dd;
            float f3 = (a0.w + slo.w) * dd;
            float f4 = (a1.x + shi.x) * dd;
            float f5 = (a1.y + shi.y) * dd;
            float f6 = (a1.z + shi.z) * dd;
            float f7 = (a1.w + shi.w) * dd;
            if (mode == 0) {
                float4 blo = *(const float4*)(bias + q * 8);
                float4 bhi = *(const float4*)(bias + q * 8 + 4);
                f0 += blo.x; f1 += blo.y; f2 += blo.z; f3 += blo.w;
                f4 += bhi.x; f5 += bhi.y; f6 += bhi.z; f7 += bhi.w;
                f0 = (f0 > 0.f ? f0 : 0.f) * dd;
                f1 = (f1 > 0.f ? f1 : 0.f) * dd;
                f2 = (f2 > 0.f ? f2 : 0.f) * dd;
                f3 = (f3 > 0.f ? f3 : 0.f) * dd;
                f4 = (f4 > 0.f ? f4 : 0.f) * dd;
                f5 = (f5 > 0.f ? f5 : 0.f) * dd;
                f6 = (f6 > 0.f ? f6 : 0.f) * dd;
                f7 = (f7 > 0.f ? f7 : 0.f) * dd;
            }
            pk4 p;
            p.h[0] = __floats2half2_rn(f0, f1);
            p.h[1] = __floats2half2_rn(f2, f3);
            p.h[2] = __floats2half2_rn(f4, f5);
            p.h[3] = __floats2half2_rn(f6, f7);
            *(uint4*)&outh[((size_t)node << 6) + (q << 3)] = p.u;
        }
    }
}

// ---------------- fallback atomic-scatter path (fp32, proven) ----------------

__global__ void k_init_deg(float* __restrict__ deg, int n) {
    int i = blockIdx.x * blockDim.x + threadIdx.x;
    if (i < n) deg[i] = 1.0f;
}

__global__ void k_deg(const int* __restrict__ dst, int E, float* __restrict__ deg) {
    int i = blockIdx.x * blockDim.x + threadIdx.x;
    if (i < E) atomicAdd(&deg[dst[i]], 1.0f);
}

__global__ void k_rsqrt(float* __restrict__ deg, int n) {
    int i = blockIdx.x * blockDim.x + threadIdx.x;
    if (i < n) deg[i] = rsqrtf(deg[i]);
}

__global__ __launch_bounds__(256) void k_gemm1_f(const float* __restrict__ x,
                                                 const float* __restrict__ W,
                                                 float* __restrict__ h, int n) {
    __shared__ float Ws[128 * 64];
    __shared__ float xsT[128 * 64];
    const int tid = threadIdx.x;
    const int row0 = blockIdx.x * 64;
    {
        const float4* Wg = (const float4*)W;
        float4* Wl = (float4*)Ws;
#pragma unroll
        for (int t = 0; t < 8; ++t) Wl[tid + t * 256] = Wg[tid + t * 256];
    }
    {
        int r = tid & 63, g = tid >> 6;
        int row = row0 + r;
        const float4* xr = (const float4*)(x + (size_t)row * 128);
#pragma unroll
        for (int t = 0; t < 8; ++t) {
            int k0 = g * 32 + t * 4;
            float4 v = (row < n) ? xr[k0 >> 2] : make_float4(0.f, 0.f, 0.f, 0.f);
            xsT[(k0 + 0) * 64 + r] = v.x;
            xsT[(k0 + 1) * 64 + r] = v.y;
            xsT[(k0 + 2) * 64 + r] = v.z;
            xsT[(k0 + 3) * 64 + r] = v.w;
        }
    }
    __syncthreads();
    const int tc = tid & 15;
    const int rg = tid >> 4;
    float acc[4][4];
#pragma unroll
    for (int i = 0; i < 4; ++i)
#pragma unroll
        for (int j = 0; j < 4; ++j) acc[i][j] = 0.f;
#pragma unroll 4
    for (int k = 0; k < 128; ++k) {
        float4 a = *(const float4*)&xsT[k * 64 + rg * 4];
        float4 b = *(const float4*)&Ws[k * 64 + tc * 4];
        acc[0][0] += a.x * b.x; acc[0][1] += a.x * b.y; acc[0][2] += a.x * b.z; acc[0][3] += a.x * b.w;
        acc[1][0] += a.y * b.x; acc[1][1] += a.y * b.y; acc[1][2] += a.y * b.z; acc[1][3] += a.y * b.w;
        acc[2][0] += a.z * b.x; acc[2][1] += a.z * b.y; acc[2][2] += a.z * b.z; acc[2][3] += a.z * b.w;
        acc[3][0] += a.w * b.x; acc[3][1] += a.w * b.y; acc[3][2] += a.w * b.z; acc[3][3] += a.w * b.w;
    }
#pragma unroll
    for (int i = 0; i < 4; ++i) {
        int row = row0 + rg * 4 + i;
        if (row < n)
            *(float4*)&h[(size_t)row * 64 + tc * 4] =
                make_float4(acc[i][0], acc[i][1], acc[i][2], acc[i][3]);
    }
}

__global__ __launch_bounds__(256) void k_gemm2_f(const float* __restrict__ agg,
                                                 const float* __restrict__ W2,
                                                 float* __restrict__ h2, int n) {
    __shared__ float Ws[64 * 40];
    __shared__ float hsT[64 * 64];
    const int tid = threadIdx.x;
    const int row0 = blockIdx.x * 64;
    {
        const float4* Wg = (const float4*)W2;
        float4* Wl = (float4*)Ws;
        for (int i = tid; i < 640; i += 256) Wl[i] = Wg[i];
    }
    {
        int r = tid & 63, g = tid >> 6;
        int row = row0 + r;
        const float4* ar = (const float4*)(agg + (size_t)row * 64);
#pragma unroll
        for (int t = 0; t < 4; ++t) {
            int k0 = g * 16 + t * 4;
            float4 v = (row < n) ? ar[k0 >> 2] : make_float4(0.f, 0.f, 0.f, 0.f);
            hsT[(k0 + 0) * 64 + r] = v.x > 0.f ? v.x : 0.f;
            hsT[(k0 + 1) * 64 + r] = v.y > 0.f ? v.y : 0.f;
            hsT[(k0 + 2) * 64 + r] = v.z > 0.f ? v.z : 0.f;
            hsT[(k0 + 3) * 64 + r] = v.w > 0.f ? v.w : 0.f;
        }
    }
    __syncthreads();
    const int tc = tid & 15;
    const int rg = tid >> 4;
    if (tc < 10) {
        float acc[4][4];
#pragma unroll
        for (int i = 0; i < 4; ++i)
#pragma unroll
            for (int j = 0; j < 4; ++j) acc[i][j] = 0.f;
#pragma unroll 4
        for (int k = 0; k < 64; ++k) {
            float4 a = *(const float4*)&hsT[k * 64 + rg * 4];
            float4 b = *(const float4*)&Ws[k * 40 + tc * 4];
            acc[0][0] += a.x * b.x; acc[0][1] += a.x * b.y; acc[0][2] += a.x * b.z; acc[0][3] += a.x * b.w;
            acc[1][0] += a.y * b.x; acc[1][1] += a.y * b.y; acc[1][2] += a.y * b.z; acc[1][3] += a.y * b.w;
            acc[2][0] += a.z * b.x; acc[2][1] += a.z * b.y; acc[2][2] += a.z * b.z; acc[2][3] += a.z * b.w;
            acc[3][0] += a.w * b.x; acc[3][1] += a.w * b.y; acc[3][2] += a.w * b.z; acc[3][3] += a.w * b.w;
        }
#pragma unroll
        for (int i = 0; i < 4; ++i) {
            int row = row0 + rg * 4 + i;
            if (row < n)
                *(float4*)&h2[(size_t)row * 40 + tc * 4] =
                    make_float4(acc[i][0], acc[i][1], acc[i][2], acc[i][3]);
        }
    }
}

__global__ void k_init_agg1(const float* __restrict__ h, const float* __restrict__ dinv,
                            const float* __restrict__ b1, float* __restrict__ agg, int n) {
    int idx = blockIdx.x * blockDim.x + threadIdx.x;
    if (idx < n * 64) {
        int i = idx >> 6, f = idx & 63;
        float d = dinv[i];
        agg[idx] = h[idx] * d * d + b1[f];
    }
}

__global__ __launch_bounds__(256) void k_scatter1(const float* __restrict__ h,
                                                  const int* __restrict__ src,
                                                  const int* __restrict__ dst,
                                                  const float* __restrict__ dinv,
                                                  float* __restrict__ agg, int E) {
    int e = blockIdx.x * 4 + (threadIdx.x >> 6);
    if (e >= E) return;
    int f = threadIdx.x & 63;
    int s = src[e], d = dst[e];
    float w = dinv[s] * dinv[d];
    atomicAdd(&agg[d * 64 + f], h[s * 64 + f] * w);
}

__global__ void k_init_out(const float* __restrict__ h2, const float* __restrict__ dinv,
                           const float* __restrict__ b2, float* __restrict__ out, int n) {
    int idx = blockIdx.x * blockDim.x + threadIdx.x;
    if (idx < n * 40) {
        int i = idx / 40;
        int f = idx - i * 40;
        float d = dinv[i];
        out[idx] = h2[idx] * d * d + b2[f];
    }
}

__global__ __launch_bounds__(256) void k_scatter2(const float* __restrict__ h2,
                                                  const int* __restrict__ src,
                                                  const int* __restrict__ dst,
                                                  const float* __restrict__ dinv,
                                                  float* __restrict__ out, int E) {
    int idx = blockIdx.x * blockDim.x + threadIdx.x;
    int total = E * 40;
    if (idx >= total) return;
    int e = idx / 40;
    int f = idx - e * 40;
    int s = src[e], d = dst[e];
    float w = dinv[s] * dinv[d];
    atomicAdd(&out[d * 40 + f], h2[s * 40 + f] * w);
}

extern "C" void kernel_launch(void* const* d_in, const int* in_sizes, int n_in,
                              void* d_out, int out_size, void* d_ws, size_t ws_size,
                              hipStream_t stream) {
    const float* x  = (const float*)d_in[0];
    const int*   ei = (const int*)d_in[1];
    const float* W1 = (const float*)d_in[2];
    const float* b1 = (const float*)d_in[3];
    const float* W2 = (const float*)d_in[4];
    const float* b2 = (const float*)d_in[5];
    float* out = (float*)d_out;

    const int n = in_sizes[0] / 128;   // 100000
    const int E = in_sizes[1] / 2;     // 1600000
    const int* src = ei;
    const int* dst = ei + E;

    char* ws = (char*)d_ws;
    const size_t MB = 1 << 20;
    float*  dinv   = (float*)(ws);                       // n floats
    int*    off    = (int*)  (ws + 512 * 1024);          // n+1 ints
    int*    bcnt   = (int*)  (ws + 1 * MB);              // NBCAP ints
    int*    bbase  = (int*)  (ws + 1 * MB + 8 * 1024);   // NBCAP+1 ints
    int*    bcur   = (int*)  (ws + 1 * MB + 16 * 1024);  // NBCAP ints
    __half* hs_h   = (__half*)(ws + 2 * MB);             // n*64 halves (12.8MB)
    __half* r2_h   = (__half*)(ws + 15 * MB);            // n*64 halves (12.8MB)
    __half* g2_h   = hs_h;                               // reuse (hs dead after gather1)
    int*    pairs  = (int*)  (ws + 28 * MB);             // E ints
    int*    csrc   = (int*)  (ws + 35 * MB);             // E ints
    size_t needed_fast = 35 * MB + (size_t)E * 4;

    const int nb = (n + NPB - 1) / NPB;

    if (ws_size >= needed_fast && nb <= NBCAP && n <= (1 << 17)) {
        // ---- CSC build via counting sort ----
        k_zero<<<(nb + 255) / 256, 256, 0, stream>>>(bcnt, nb);
        k_hist<<<512, 256, 0, stream>>>(dst, E, bcnt, nb);
        k_scan_nb<<<1, 512, 0, stream>>>(bcnt, bbase, bcur, nb);
        k_binpass<<<(E + 4095) / 4096, 256, 0, stream>>>(src, dst, bcur, pairs, nb, E);
        k_bucket_build<<<nb, 256, 0, stream>>>(pairs, bbase, off, csrc, dinv, n, nb);

        const int GB = 2048;                 // persistent gather blocks
        const int NW = GB * 4;               // waves

        // ---- layer 1: hs = (x@W1)*dinv; r2 = relu(Ahat-agg + b1)*dinv ----
        k_gemm1_h<<<(n + 63) / 64, 256, 0, stream>>>(x, W1, hs_h, n, dinv);
        k_gather_h<<<GB, 256, 0, stream>>>(hs_h, off, csrc, dinv, b1, r2_h, n, NW, 0);

        // ---- layer 2: g2 = Ahat-agg(r2); out = g2 @ W2 + b2 ----
        k_gather_h<<<GB, 256, 0, stream>>>(r2_h, off, csrc, dinv, b1, g2_h, n, NW, 1);
        k_gemm2_out<<<(n + 63) / 64, 256, 0, stream>>>(g2_h, W2, b2, out, n);
    } else {
        // ---- fallback: fp32 atomic scatter path ----
        float* hlin = (float*)(ws + 2 * MB);
        float* agg1 = (float*)(ws + 28 * MB);
        k_init_deg<<<(n + 255) / 256, 256, 0, stream>>>(dinv, n);
        k_deg<<<(E + 255) / 256, 256, 0, stream>>>(dst, E, dinv);
        k_rsqrt<<<(n + 255) / 256, 256, 0, stream>>>(dinv, n);
        k_gemm1_f<<<(n + 63) / 64, 256, 0, stream>>>(x, W1, hlin, n);
        k_init_agg1<<<(n * 64 + 255) / 256, 256, 0, stream>>>(hlin, dinv, b1, agg1, n);
        k_scatter1<<<(E + 3) / 4, 256, 0, stream>>>(hlin, src, dst, dinv, agg1, E);
        k_gemm2_f<<<(n + 63) / 64, 256, 0, stream>>>(agg1, W2, hlin, n);
        k_init_out<<<(n * 40 + 255) / 256, 256, 0, stream>>>(hlin, dinv, b2, out, n);
        int total2 = E * 40;
        k_scatter2<<<(total2 + 255) / 256, 256, 0, stream>>>(hlin, src, dst, dinv, out, E);
    }
}